// Round 5
// baseline (5918.607 us; speedup 1.0000x reference)
//
#include <hip/hip_runtime.h>
#include <hip/hip_bf16.h>

#define NP 63   // number of patches

typedef __attribute__((ext_vector_type(8))) short short8;
typedef __attribute__((ext_vector_type(4))) float f32x4;
typedef __attribute__((ext_vector_type(4))) int i32x4;
typedef unsigned char uchar;

__device__ __forceinline__ float sigf(float x){ return 1.0f/(1.0f+expf(-x)); }
__device__ __forceinline__ float u2f(ushort u){ __hip_bfloat16 h; *(ushort*)&h = u; return __bfloat162float(h); }
__device__ __forceinline__ ushort f2u(float f){ __hip_bfloat16 h = __float2bfloat16(f); return *(ushort*)&h; }

// all 4 bytes of dword d >= tag ?
__device__ __forceinline__ bool bytes_ok(uint d, uint tag){
  return ((d & 0xffu) >= tag) & (((d>>8) & 0xffu) >= tag) &
         (((d>>16) & 0xffu) >= tag) & ((d>>24) >= tag);
}

// ---------------- RevIN stats (+ zero persistent-scan flag bytes) ----------------
__global__ void __launch_bounds__(256) k_revin(const float* __restrict__ series,
    float* __restrict__ meanv, float* __restrict__ stdv, int* __restrict__ bar)
{
  int n = blockIdx.x, tid = threadIdx.x;
  if(n==0){ for(int i=tid;i<1024;i+=256) bar[i]=0; }  // 4 layers x 16 groups x 64 flag bytes
  __shared__ float s1[256], s2[256];
  const float* p = series + n*512;
  float a = 0.f, b = 0.f;
  for(int t=tid;t<512;t+=256){ float v=p[t]; a+=v; b+=v*v; }
  s1[tid]=a; s2[tid]=b; __syncthreads();
  for(int s=128;s>0;s>>=1){
    if(tid<s){ s1[tid]+=s1[tid+s]; s2[tid]+=s2[tid+s]; }
    __syncthreads();
  }
  if(tid==0){
    float mu = s1[0]*(1.f/512.f);
    float var = fmaxf(s2[0]*(1.f/512.f) - mu*mu, 0.f);
    meanv[n]=mu; stdv[n]=sqrtf(var+1e-5f);
  }
}

// ---------------- patch embed -> bf16 xbuf ----------------
__global__ void __launch_bounds__(256) k_patch(const float* __restrict__ series,
    const float* __restrict__ rs, const float* __restrict__ rb,
    const float* __restrict__ up_w, const float* __restrict__ meanv,
    const float* __restrict__ stdv, ushort* __restrict__ x)
{
  int n = blockIdx.x, tid = threadIdx.x;
  int m = n & 7;
  __shared__ float sn[512];
  float mu = meanv[n], sd = stdv[n];
  float A = rs[m]/sd, C = rb[m] - mu*A;
  const float* p = series + n*512;
  for(int t=tid;t<512;t+=256) sn[t] = p[t]*A + C;
  __syncthreads();
  float w[16];
  #pragma unroll
  for(int i=0;i<16;i++) w[i] = up_w[i*256+tid];
  ushort* xo = x + n*(NP*256);
  for(int pi=0;pi<NP;pi++){
    float acc=0.f;
    #pragma unroll
    for(int i=0;i<16;i++) acc = fmaf(sn[pi*8+i], w[i], acc);
    xo[pi*256+tid] = f2u(acc);
  }
}

// ---------------- W_od = wo @ down_w (f32) ----------------
__global__ void __launch_bounds__(256) k_wod(const float* __restrict__ wo,
    const float* __restrict__ dw, float* __restrict__ wod)
{
  int i = blockIdx.x, blk = blockIdx.y, tid = threadIdx.x;
  __shared__ float row[512];
  const float* wr = wo + (blk*512 + i)*512;
  for(int k=tid;k<512;k+=256) row[k]=wr[k];
  __syncthreads();
  const float* d = dw + blk*512*256;
  float acc=0.f;
  for(int k=0;k<512;k++) acc = fmaf(row[k], d[k*256+tid], acc);
  wod[(blk*512+i)*256+tid]=acc;
}

// ---------------- transpose wod (512k x 256n) -> wodt bf16 [256][512] ----------------
__global__ void __launch_bounds__(256) k_tr_wodt(const float* __restrict__ wod, ushort* __restrict__ wodt)
{
  __shared__ float tile[32][33];
  int blk = blockIdx.z;
  int n0 = blockIdx.x*32, k0 = blockIdx.y*32;
  int tid = threadIdx.x;
  #pragma unroll
  for(int i=0;i<4;i++){
    int idx = tid + 256*i; int kl = idx>>5, nl = idx&31;
    tile[kl][nl] = wod[blk*512*256 + (k0+kl)*256 + n0+nl];
  }
  __syncthreads();
  #pragma unroll
  for(int i=0;i<4;i++){
    int idx = tid + 256*i; int nl = idx>>5, kl = idx&31;
    wodt[blk*256*512 + (n0+nl)*512 + k0+kl] = f2u(tile[kl][nl]);
  }
}

// ---------------- transpose [wi;wh] (768k x 2048n) -> wt bf16 [2048][768] ----------------
__global__ void __launch_bounds__(256) k_tr_lstmw(const float* __restrict__ wi,
    const float* __restrict__ wh, ushort* __restrict__ wt)
{
  __shared__ float tile[32][33];
  int blk = blockIdx.z;
  int n0 = blockIdx.x*32, k0 = blockIdx.y*32;
  int tid = threadIdx.x;
  #pragma unroll
  for(int i=0;i<4;i++){
    int idx = tid + 256*i; int kl = idx>>5, nl = idx&31;
    int k = k0+kl, n = n0+nl;
    float v = (k<256) ? wi[blk*256*2048 + k*2048 + n]
                      : wh[blk*512*2048 + (k-256)*2048 + n];
    tile[kl][nl] = v;
  }
  __syncthreads();
  #pragma unroll
  for(int i=0;i<4;i++){
    int idx = tid + 256*i; int nl = idx>>5, kl = idx&31;
    wt[blk*2048*768 + (n0+nl)*768 + k0+kl] = f2u(tile[kl][nl]);
  }
}

// ---------------- transpose [wq|wk|wv] (512k x 768n), fold ns[k] -> wqkvt bf16 [768][512] ----------------
__global__ void __launch_bounds__(256) k_tr_qkvw(const float* __restrict__ wq,
    const float* __restrict__ wk, const float* __restrict__ wv,
    const float* __restrict__ ns, ushort* __restrict__ wqkvt)
{
  __shared__ float tile[32][33];
  int blk = blockIdx.z;
  int n0 = blockIdx.x*32, k0 = blockIdx.y*32;
  int tid = threadIdx.x;
  #pragma unroll
  for(int i=0;i<4;i++){
    int idx = tid + 256*i; int kl = idx>>5, nl = idx&31;
    int k = k0+kl, n = n0+nl;
    float v;
    if(n < 512)      v = wq[blk*512*512 + k*512 + n];
    else if(n < 640) v = wk[blk*512*128 + k*128 + (n-512)];
    else             v = wv[blk*512*128 + k*128 + (n-640)];
    tile[kl][nl] = v * ns[blk*512 + k];
  }
  __syncthreads();
  #pragma unroll
  for(int i=0;i<4;i++){
    int idx = tid + 256*i; int nl = idx>>5, kl = idx&31;
    wqkvt[blk*768*512 + (n0+nl)*512 + k0+kl] = f2u(tile[kl][nl]);
  }
}

// ---------------- persistent LSTM scan: dataflow-synced, all 63 steps in one launch ----------------
// 256 blocks x 256 thr (1 block/CU, 128 KB LDS). Block = (row group g: 64 rows) x (jj tile y: 32 jj x 4 gates).
// DEPENDENCY IS 1:1 — wh A-chunk ck reads h columns [32ck,32ck+32) which producer block y=ck wrote.
// Sync per producer: chunk ck waits on producer ck's 4 per-wave flag bytes
// (flags[g*64 + ck*4 + wave], monotonic tag = t+1, sc1). Flag snapshot (4x16B) prefetched at step
// start and consumed after the wi-phase -> ~zero exposed wait in steady state. NO intra-block
// barriers in the loop: h stored directly from epilogue regs (sc1), each wave drains vmcnt(0)
// and publishes its own flag. MFMA order identical to the round-3 passing kernel (bit-identical).
__global__ void __launch_bounds__(256,1) k_lstm_scan(
    const ushort* __restrict__ x, ushort* __restrict__ hs,
    const ushort* __restrict__ wt, const float* __restrict__ bias,
    uchar* __restrict__ flags)
{
  __shared__ __align__(16) short Bwh[128*512];     // 128 KB: wh k 256..767, row c = gate*32+jjl, swizzled
  int fb = blockIdx.x;
  // XCD-grouping heuristic: members of a barrier group share blockIdx%8 -> same XCD
  int g = (fb & 7) | ((fb >> 4) & 8);
  int y = (fb >> 3) & 15;
  int n0 = g*64, jj0 = y*32;
  int tid = threadIdx.x;
  int wv = tid>>6, lane = tid&63, quad = lane>>4, l16 = lane&15;
  int wrow = wv>>1, wcol = wv&1;

  // fill Bwh: 128 c-rows x 64 short8 (k 256..767), 16B-block XOR swizzle by (c&7)
  for(int i=tid; i<8192; i+=256){
    int c = i>>6, kb = i&63;
    short8 v = *(const short8*)(wt + ((c>>5)*512 + jj0 + (c&31))*768 + 256 + kb*8);
    *(short8*)((char*)Bwh + c*1024 + ((kb*16) ^ ((c&7)<<4))) = v;
  }
  // wi B-fragments -> regs (4 gates x 8 k-chunks)
  int jj = jj0 + wcol*16 + l16;
  short8 bwi[4][8];
  #pragma unroll
  for(int gg=0; gg<4; gg++){
    const ushort* wp = wt + (gg*512 + jj)*768 + quad*8;
    #pragma unroll
    for(int ck=0; ck<8; ck++) bwi[gg][ck] = *(const short8*)(wp + ck*32);
  }
  float bI=bias[jj], bF=bias[512+jj], bG=bias[1024+jj], bO=bias[1536+jj];
  float cs[2][4];
  #pragma unroll
  for(int a=0;a<2;a++){
    #pragma unroll
    for(int r=0;r<4;r++) cs[a][r]=0.f;
  }
  const ushort* xb0 = x  + (n0 + wrow*32 + l16)*(NP*256) + quad*8;
  const ushort* hb0 = hs + (n0 + wrow*32 + l16)*(NP*512) + quad*8;
  int xorb = (l16&7)<<4;
  const uchar* gflags = flags + g*64;
  uchar* myflag = flags + g*64 + y*4 + wv;
  __syncthreads();   // Bwh ready; the ONLY block barrier (Bwh is read-only afterwards)

  for(int t=0; t<NP; ++t){
    i32x4 f0, f1, f2, f3;
    if(t > 0){
      // prefetch flag snapshot (4 x 16B, sc1); waited after the wi-phase
      asm volatile("global_load_dwordx4 %0, %1, off sc0 sc1" : "=&v"(f0) : "v"(gflags)    );
      asm volatile("global_load_dwordx4 %0, %1, off sc0 sc1" : "=&v"(f1) : "v"(gflags+16) );
      asm volatile("global_load_dwordx4 %0, %1, off sc0 sc1" : "=&v"(f2) : "v"(gflags+32) );
      asm volatile("global_load_dwordx4 %0, %1, off sc0 sc1" : "=&v"(f3) : "v"(gflags+48) );
    }

    f32x4 acc[4][2];
    #pragma unroll
    for(int gg=0; gg<4; gg++){ acc[gg][0]=(f32x4){0.f,0.f,0.f,0.f}; acc[gg][1]=(f32x4){0.f,0.f,0.f,0.f}; }

    // ---- x_t @ wi (k 0..255) — no recurrent dep, hides the flag-snapshot latency ----
    #pragma unroll
    for(int ck=0; ck<8; ck++){
      short8 a0 = *(const short8*)(xb0 + t*256 + ck*32);
      short8 a1 = *(const short8*)(xb0 + 16*(NP*256) + t*256 + ck*32);
      #pragma unroll
      for(int gg=0; gg<4; gg++){
        acc[gg][0] = __builtin_amdgcn_mfma_f32_16x16x32_bf16(a0, bwi[gg][ck], acc[gg][0], 0,0,0);
        acc[gg][1] = __builtin_amdgcn_mfma_f32_16x16x32_bf16(a1, bwi[gg][ck], acc[gg][1], 0,0,0);
      }
    }

    if(t > 0){
      // snapshot arrived; "memory" orders all later h loads after this point
      asm volatile("s_waitcnt vmcnt(0)" : "+v"(f0), "+v"(f1), "+v"(f2), "+v"(f3) :: "memory");
      const ushort* hb = hb0 + (t-1)*512;
      uint tag = (uint)t;
      // ---- per-producer dataflow (1:1): wait producer ck's flags, then MFMA chunk ck ----
      #pragma unroll
      for(int yy=0; yy<16; yy++){
        uint d;
        if(yy<4)       d = (uint)f0[yy&3];
        else if(yy<8)  d = (uint)f1[yy&3];
        else if(yy<12) d = (uint)f2[yy&3];
        else           d = (uint)f3[yy&3];
        if(!bytes_ok(d, tag)){
          const uchar* qa = gflags + (yy>>2)*16;
          i32x4 fr;
          do {
            __builtin_amdgcn_s_sleep(1);
            asm volatile("global_load_dwordx4 %0, %1, off sc0 sc1\n\ts_waitcnt vmcnt(0)"
                         : "=&v"(fr) : "v"(qa) : "memory");
            d = (uint)fr[yy&3];
          } while(!bytes_ok(d, tag));
        }
        {
          const int ck = yy;
          short8 a0 = *(const short8*)(hb + ck*32);
          short8 a1 = *(const short8*)(hb + 16*(NP*512) + ck*32);
          #pragma unroll
          for(int gg=0; gg<4; gg++){
            int c = gg*32 + wcol*16 + l16;
            short8 bh = *(short8*)((char*)Bwh + c*1024 + ((ck*64 + quad*16) ^ xorb));
            acc[gg][0] = __builtin_amdgcn_mfma_f32_16x16x32_bf16(a0, bh, acc[gg][0], 0,0,0);
            acc[gg][1] = __builtin_amdgcn_mfma_f32_16x16x32_bf16(a1, bh, acc[gg][1], 0,0,0);
          }
        }
      }
    }

    // ---- gates + c-state (regs) + direct device-visible h store ----
    #pragma unroll
    for(int a=0;a<2;a++){
      #pragma unroll
      for(int r=0;r<4;r++){
        int n = n0 + wrow*32 + a*16 + quad*4 + r;
        float zi=acc[0][a][r]+bI, zf=acc[1][a][r]+bF, zg=acc[2][a][r]+bG, zo=acc[3][a][r]+bO;
        float c = sigf(zf)*cs[a][r] + sigf(zi)*tanhf(zg);
        cs[a][r] = c;
        ushort hv = f2u(sigf(zo)*tanhf(c));
        ushort* gp = hs + ((size_t)n*NP + t)*512 + jj;
        asm volatile("global_store_short %0, %1, off sc0 sc1" :: "v"(gp), "v"(hv) : "memory");
      }
    }
    // ---- per-wave: drain own stores, then publish own flag byte (no block barrier) ----
    if(t < NP-1){
      asm volatile("s_waitcnt vmcnt(0)" ::: "memory");
      uint tv = (uint)(t+1);
      asm volatile("global_store_byte %0, %1, off sc0 sc1" :: "v"(myflag), "v"(tv) : "memory");
    }
  }
}

// ---------------- rms_inv over H2=512 for attention rows ----------------
__global__ void __launch_bounds__(256) k_rms(const ushort* __restrict__ hs, float* __restrict__ rmsi)
{
  int tid = threadIdx.x;
  int r = blockIdx.x*4 + (tid>>6);
  int lane = tid&63;
  int bq = r/8064; int rr = r - bq*8064;
  int m = rr/1008; int rem = rr - m*1008;
  int p = rem>>4; int d = rem&15;
  int n = (bq*16+d)*8+m;
  const ushort* hp = hs + (n*NP+p)*512;
  float s=0.f;
  for(int c=lane;c<512;c+=64){ float v=u2f(hp[c]); s += v*v; }
  #pragma unroll
  for(int off=32;off>0;off>>=1) s += __shfl_down(s,off);
  if(lane==0) rmsi[r] = rsqrtf(s*(1.f/512.f)+1e-6f);
}

// ---------------- qkv GEMM via MFMA: 64512 x 768, K=512; rms applied on output ----------------
__global__ void __launch_bounds__(256) k_qkv_m(
    const ushort* __restrict__ hs, const float* __restrict__ rmsi,
    const ushort* __restrict__ wqkvt, ushort* __restrict__ qkv)
{
  __shared__ short As[64*40];
  __shared__ short Bs[128*40];
  int tid = threadIdx.x;
  int r0 = blockIdx.x*64, c0 = blockIdx.y*128;
  int wv = tid>>6, lane = tid&63, quad = lane>>4, l16 = lane&15;
  int arow = tid>>2, akp = tid&3;
  int r = r0 + arow;
  int bq = r/8064; int rr = r - bq*8064;
  int m = rr/1008; int rem = rr - m*1008;
  int p = rem>>4; int d = rem&15;
  int n = (bq*16+d)*8+m;
  const ushort* aptr = hs + (n*NP+p)*512 + akp*8;
  f32x4 acc[2][4];
  #pragma unroll
  for(int b=0;b<2;b++){
    #pragma unroll
    for(int a=0;a<4;a++) acc[b][a] = (f32x4){0.f,0.f,0.f,0.f};
  }
  for(int k0=0;k0<512;k0+=32){
    *(short8*)&As[arow*40+akp*8] = *(const short8*)(aptr + k0);
    #pragma unroll
    for(int i=0;i<2;i++){
      int pc = tid + 256*i; int rl=pc>>2, kp=pc&3;
      *(short8*)&Bs[rl*40+kp*8] = *(const short8*)(wqkvt + (c0+rl)*512 + k0 + kp*8);
    }
    __syncthreads();
    short8 af[4], bfr[2];
    #pragma unroll
    for(int a=0;a<4;a++) af[a] = *(short8*)&As[(a*16+l16)*40 + quad*8];
    #pragma unroll
    for(int b=0;b<2;b++) bfr[b] = *(short8*)&Bs[(wv*32+b*16+l16)*40 + quad*8];
    #pragma unroll
    for(int b=0;b<2;b++){
      #pragma unroll
      for(int a=0;a<4;a++)
        acc[b][a] = __builtin_amdgcn_mfma_f32_16x16x32_bf16(af[a], bfr[b], acc[b][a], 0,0,0);
    }
    __syncthreads();
  }
  #pragma unroll
  for(int a=0;a<4;a++){
    #pragma unroll
    for(int rg=0;rg<4;rg++){
      int rw = r0 + a*16 + quad*4 + rg;
      float rv = rmsi[rw];
      #pragma unroll
      for(int b=0;b<2;b++){
        int c = c0 + wv*32 + b*16 + l16;
        qkv[rw*768 + c] = f2u(acc[b][a][rg] * rv);
      }
    }
  }
}

// ---------------- attention (bf16 qkv buffer): per (row16-group, head) ----------------
__global__ void __launch_bounds__(256) k_attn(ushort* __restrict__ qkv)
{
  int r3 = blockIdx.x, h = blockIdx.y;
  int tid = threadIdx.x;
  __shared__ float qs[16][64];
  __shared__ float ks[16][65];
  __shared__ float vs[16][64];
  __shared__ float P[16][17];
  ushort* base = qkv + r3*16*768;
  int xx = tid&63, s4 = tid>>6;
  int kvh = (h>>2)*64;
  #pragma unroll
  for(int a=0;a<4;a++){
    int s = s4 + 4*a;
    qs[s][xx] = u2f(base[s*768 + h*64 + xx]);
    ks[s][xx] = u2f(base[s*768 + 512 + kvh + xx]);
    vs[s][xx] = u2f(base[s*768 + 640 + kvh + xx]);
  }
  __syncthreads();
  int i = tid>>4, j = tid&15;
  float sc = 0.f;
  #pragma unroll
  for(int xq=0;xq<64;xq++) sc = fmaf(qs[i][xq], ks[j][xq], sc);
  P[i][j] = sc*0.125f;
  __syncthreads();
  float row[16];
  #pragma unroll
  for(int jj=0;jj<16;jj++) row[jj] = P[i][jj];
  float mx = row[0];
  #pragma unroll
  for(int jj=1;jj<16;jj++) mx = fmaxf(mx, row[jj]);
  float sum = 0.f;
  #pragma unroll
  for(int jj=0;jj<16;jj++) sum += expf(row[jj]-mx);
  float pme = expf(row[j]-mx)/sum;
  __syncthreads();
  P[i][j] = pme;
  __syncthreads();
  #pragma unroll
  for(int a=0;a<4;a++){
    int s = s4 + 4*a;
    float o = 0.f;
    #pragma unroll
    for(int jj=0;jj<16;jj++) o = fmaf(P[s][jj], vs[jj][xx], o);
    base[s*768 + h*64 + xx] = f2u(o);
  }
}

// ---------------- bel GEMM via MFMA: O(64512x512 in qkv) @ wodt^T -> scatter bf16 xbuf ----------------
__global__ void __launch_bounds__(256) k_bel_m(
    const ushort* __restrict__ qkv, const ushort* __restrict__ wodt,
    ushort* __restrict__ x)
{
  __shared__ short As[64*40];
  __shared__ short Bs[128*40];
  int tid = threadIdx.x;
  int r0 = blockIdx.x*64, c0 = blockIdx.y*128;
  int wv = tid>>6, lane = tid&63, quad = lane>>4, l16 = lane&15;
  int arow = tid>>2, akp = tid&3;
  const ushort* aptr = qkv + (r0+arow)*768 + akp*8;
  f32x4 acc[2][4];
  #pragma unroll
  for(int b=0;b<2;b++){
    #pragma unroll
    for(int a=0;a<4;a++) acc[b][a] = (f32x4){0.f,0.f,0.f,0.f};
  }
  for(int k0=0;k0<512;k0+=32){
    *(short8*)&As[arow*40+akp*8] = *(const short8*)(aptr + k0);
    #pragma unroll
    for(int i=0;i<2;i++){
      int pc = tid + 256*i; int rl=pc>>2, kp=pc&3;
      *(short8*)&Bs[rl*40+kp*8] = *(const short8*)(wodt + (c0+rl)*512 + k0 + kp*8);
    }
    __syncthreads();
    short8 af[4], bfr[2];
    #pragma unroll
    for(int a=0;a<4;a++) af[a] = *(short8*)&As[(a*16+l16)*40 + quad*8];
    #pragma unroll
    for(int b=0;b<2;b++) bfr[b] = *(short8*)&Bs[(wv*32+b*16+l16)*40 + quad*8];
    #pragma unroll
    for(int b=0;b<2;b++){
      #pragma unroll
      for(int a=0;a<4;a++)
        acc[b][a] = __builtin_amdgcn_mfma_f32_16x16x32_bf16(af[a], bfr[b], acc[b][a], 0,0,0);
    }
    __syncthreads();
  }
  #pragma unroll
  for(int a=0;a<4;a++){
    #pragma unroll
    for(int rg=0;rg<4;rg++){
      int rw = r0 + a*16 + quad*4 + rg;
      int bq = rw/8064; int rr = rw - bq*8064;
      int m = rr/1008; int rem = rr - m*1008;
      int p = rem>>4; int d = rem&15;
      int n = (bq*16+d)*8+m;
      ushort* xo = x + (n*NP+p)*256;
      #pragma unroll
      for(int b=0;b<2;b++){
        int c = c0 + wv*32 + b*16 + l16;
        xo[c] = f2u(acc[b][a][rg]);
      }
    }
  }
}

// ---------------- head ----------------
__global__ void __launch_bounds__(256) k_head(const ushort* __restrict__ x,
    const float* __restrict__ meanv, const float* __restrict__ stdv,
    const float* __restrict__ rs, const float* __restrict__ rb,
    const float* __restrict__ hns, const float* __restrict__ pw,
    const float* __restrict__ qw, float* __restrict__ out)
{
  int n = blockIdx.x, tid = threadIdx.x;
  __shared__ float nb[256];
  __shared__ float red[256];
  float v = u2f(x[(n*NP + 62)*256 + tid]);
  red[tid] = v*v; __syncthreads();
  for(int s=128;s>0;s>>=1){
    if(tid<s) red[tid]+=red[tid+s];
    __syncthreads();
  }
  float rinv = rsqrtf(red[0]*(1.f/256.f)+1e-6f);
  nb[tid] = v*rinv*hns[tid];
  __syncthreads();
  int m = n&7;
  float mu=meanv[n], sd=stdv[n], sc=rs[m], bi=rb[m];
  for(int col=tid; col<384; col+=256){
    float acc=0.f;
    int slot, hh;
    if(col < 96){
      for(int k=0;k<256;k++) acc = fmaf(nb[k], pw[k*96+col], acc);
      slot = 0; hh = col;
    } else {
      int cq = col-96;
      for(int k=0;k<256;k++) acc = fmaf(nb[k], qw[k*288+cq], acc);
      int qi = cq - (cq/3)*3;
      slot = 1 + qi; hh = cq/3;
    }
    float y = (acc - bi)/sc*sd + mu;
    out[(slot*1024 + n)*96 + hh] = y;
  }
}

extern "C" void kernel_launch(void* const* d_in, const int* in_sizes, int n_in,
                              void* d_out, int out_size, void* d_ws, size_t ws_size,
                              hipStream_t stream)
{
  const float* series    = (const float*)d_in[0];
  const float* rs        = (const float*)d_in[1];
  const float* rb        = (const float*)d_in[2];
  const float* up_w      = (const float*)d_in[3];
  const float* lstm_wi   = (const float*)d_in[4];
  const float* lstm_wh   = (const float*)d_in[5];
  const float* lstm_b    = (const float*)d_in[6];
  const float* norm_scale= (const float*)d_in[7];
  const float* wq        = (const float*)d_in[8];
  const float* wk        = (const float*)d_in[9];
  const float* wv        = (const float*)d_in[10];
  const float* wo        = (const float*)d_in[11];
  const float* down_w    = (const float*)d_in[12];
  const float* head_ns   = (const float*)d_in[13];
  const float* point_w   = (const float*)d_in[14];
  const float* quant_w   = (const float*)d_in[15];
  float* out = (float*)d_out;

  float* ws = (float*)d_ws;
  float*  meanv = ws;                       // 1024
  float*  stdv  = meanv + 1024;             // 1024
  float*  rmsi  = stdv  + 1024;             // 64512
  float*  cst   = rmsi  + 64512;            // 524288 (c-state in regs; start reused for flag bytes)
  float*  wodf  = cst   + 524288;           // 524288
  ushort* xbuf  = (ushort*)(wodf + 524288);         // 16515072 bf16
  ushort* hsb   = xbuf  + 16515072;                 // 33030144 bf16
  ushort* qkvb  = hsb   + 33030144;                 // 49545216 bf16
  ushort* wt    = qkvb  + 49545216;                 // 6291456 bf16
  ushort* wqkvt = wt    + 6291456;                  // 1572864 bf16
  ushort* wodt  = wqkvt + 1572864;                  // 524288 bf16
  uchar*  flagb = (uchar*)cst;                      // 4 layers x 16 groups x 64 flag bytes

  k_revin<<<1024,256,0,stream>>>(series, meanv, stdv, (int*)flagb);
  k_patch<<<1024,256,0,stream>>>(series, rs, rb, up_w, meanv, stdv, xbuf);
  k_wod<<<dim3(512,4),256,0,stream>>>(wo, down_w, wodf);
  k_tr_wodt<<<dim3(8,16,4),256,0,stream>>>(wodf, wodt);
  k_tr_lstmw<<<dim3(64,24,4),256,0,stream>>>(lstm_wi, lstm_wh, wt);
  k_tr_qkvw<<<dim3(24,16,4),256,0,stream>>>(wq, wk, wv, norm_scale, wqkvt);

  for(int blk=0; blk<4; blk++){
    const ushort* wt_b = wt + blk*2048*768;
    const float*  bb   = lstm_b + blk*2048;
    k_lstm_scan<<<256,256,0,stream>>>(xbuf, hsb, wt_b, bb, flagb + blk*1024);
    k_rms<<<16128,256,0,stream>>>(hsb, rmsi);
    k_qkv_m<<<dim3(1008,6),256,0,stream>>>(hsb, rmsi, wqkvt + blk*768*512, qkvb);
    k_attn<<<dim3(4032,8),256,0,stream>>>(qkvb);
    k_bel_m<<<dim3(1008,2),256,0,stream>>>(qkvb, wodt + blk*256*512, xbuf);
  }
  k_head<<<1024,256,0,stream>>>(xbuf, meanv, stdv, rs, rb, head_ns, point_w, quant_w, out);
}

// Round 6
// 4351.432 us; speedup vs baseline: 1.3602x; 1.3602x over previous
//
#include <hip/hip_runtime.h>
#include <hip/hip_bf16.h>

#define NP 63   // number of patches

typedef __attribute__((ext_vector_type(8))) short short8;
typedef __attribute__((ext_vector_type(4))) float f32x4;
typedef __attribute__((ext_vector_type(4))) int i32x4;
typedef unsigned char uchar;

__device__ __forceinline__ float sigf(float x){ return 1.0f/(1.0f+expf(-x)); }
__device__ __forceinline__ float u2f(ushort u){ __hip_bfloat16 h; *(ushort*)&h = u; return __bfloat162float(h); }
__device__ __forceinline__ ushort f2u(float f){ __hip_bfloat16 h = __float2bfloat16(f); return *(ushort*)&h; }

// all 4 bytes of dword d >= tag ?
__device__ __forceinline__ bool bytes_ok(uint d, uint tag){
  return ((d & 0xffu) >= tag) & (((d>>8) & 0xffu) >= tag) &
         (((d>>16) & 0xffu) >= tag) & ((d>>24) >= tag);
}

// ---------------- RevIN stats (+ zero persistent-scan flag bytes) ----------------
__global__ void __launch_bounds__(256) k_revin(const float* __restrict__ series,
    float* __restrict__ meanv, float* __restrict__ stdv, int* __restrict__ bar)
{
  int n = blockIdx.x, tid = threadIdx.x;
  if(n==0){ for(int i=tid;i<1024;i+=256) bar[i]=0; }  // 4 layers x 16 groups x 64 flag bytes
  __shared__ float s1[256], s2[256];
  const float* p = series + n*512;
  float a = 0.f, b = 0.f;
  for(int t=tid;t<512;t+=256){ float v=p[t]; a+=v; b+=v*v; }
  s1[tid]=a; s2[tid]=b; __syncthreads();
  for(int s=128;s>0;s>>=1){
    if(tid<s){ s1[tid]+=s1[tid+s]; s2[tid]+=s2[tid+s]; }
    __syncthreads();
  }
  if(tid==0){
    float mu = s1[0]*(1.f/512.f);
    float var = fmaxf(s2[0]*(1.f/512.f) - mu*mu, 0.f);
    meanv[n]=mu; stdv[n]=sqrtf(var+1e-5f);
  }
}

// ---------------- patch embed -> bf16 xbuf ----------------
__global__ void __launch_bounds__(256) k_patch(const float* __restrict__ series,
    const float* __restrict__ rs, const float* __restrict__ rb,
    const float* __restrict__ up_w, const float* __restrict__ meanv,
    const float* __restrict__ stdv, ushort* __restrict__ x)
{
  int n = blockIdx.x, tid = threadIdx.x;
  int m = n & 7;
  __shared__ float sn[512];
  float mu = meanv[n], sd = stdv[n];
  float A = rs[m]/sd, C = rb[m] - mu*A;
  const float* p = series + n*512;
  for(int t=tid;t<512;t+=256) sn[t] = p[t]*A + C;
  __syncthreads();
  float w[16];
  #pragma unroll
  for(int i=0;i<16;i++) w[i] = up_w[i*256+tid];
  ushort* xo = x + n*(NP*256);
  for(int pi=0;pi<NP;pi++){
    float acc=0.f;
    #pragma unroll
    for(int i=0;i<16;i++) acc = fmaf(sn[pi*8+i], w[i], acc);
    xo[pi*256+tid] = f2u(acc);
  }
}

// ---------------- W_od = wo @ down_w (f32) ----------------
__global__ void __launch_bounds__(256) k_wod(const float* __restrict__ wo,
    const float* __restrict__ dw, float* __restrict__ wod)
{
  int i = blockIdx.x, blk = blockIdx.y, tid = threadIdx.x;
  __shared__ float row[512];
  const float* wr = wo + (blk*512 + i)*512;
  for(int k=tid;k<512;k+=256) row[k]=wr[k];
  __syncthreads();
  const float* d = dw + blk*512*256;
  float acc=0.f;
  for(int k=0;k<512;k++) acc = fmaf(row[k], d[k*256+tid], acc);
  wod[(blk*512+i)*256+tid]=acc;
}

// ---------------- transpose wod (512k x 256n) -> wodt bf16 [256][512] ----------------
__global__ void __launch_bounds__(256) k_tr_wodt(const float* __restrict__ wod, ushort* __restrict__ wodt)
{
  __shared__ float tile[32][33];
  int blk = blockIdx.z;
  int n0 = blockIdx.x*32, k0 = blockIdx.y*32;
  int tid = threadIdx.x;
  #pragma unroll
  for(int i=0;i<4;i++){
    int idx = tid + 256*i; int kl = idx>>5, nl = idx&31;
    tile[kl][nl] = wod[blk*512*256 + (k0+kl)*256 + n0+nl];
  }
  __syncthreads();
  #pragma unroll
  for(int i=0;i<4;i++){
    int idx = tid + 256*i; int nl = idx>>5, kl = idx&31;
    wodt[blk*256*512 + (n0+nl)*512 + k0+kl] = f2u(tile[kl][nl]);
  }
}

// ---------------- transpose [wi;wh] (768k x 2048n) -> wt bf16 [2048][768] ----------------
__global__ void __launch_bounds__(256) k_tr_lstmw(const float* __restrict__ wi,
    const float* __restrict__ wh, ushort* __restrict__ wt)
{
  __shared__ float tile[32][33];
  int blk = blockIdx.z;
  int n0 = blockIdx.x*32, k0 = blockIdx.y*32;
  int tid = threadIdx.x;
  #pragma unroll
  for(int i=0;i<4;i++){
    int idx = tid + 256*i; int kl = idx>>5, nl = idx&31;
    int k = k0+kl, n = n0+nl;
    float v = (k<256) ? wi[blk*256*2048 + k*2048 + n]
                      : wh[blk*512*2048 + (k-256)*2048 + n];
    tile[kl][nl] = v;
  }
  __syncthreads();
  #pragma unroll
  for(int i=0;i<4;i++){
    int idx = tid + 256*i; int nl = idx>>5, kl = idx&31;
    wt[blk*2048*768 + (n0+nl)*768 + k0+kl] = f2u(tile[kl][nl]);
  }
}

// ---------------- transpose [wq|wk|wv] (512k x 768n), fold ns[k] -> wqkvt bf16 [768][512] ----------------
__global__ void __launch_bounds__(256) k_tr_qkvw(const float* __restrict__ wq,
    const float* __restrict__ wk, const float* __restrict__ wv,
    const float* __restrict__ ns, ushort* __restrict__ wqkvt)
{
  __shared__ float tile[32][33];
  int blk = blockIdx.z;
  int n0 = blockIdx.x*32, k0 = blockIdx.y*32;
  int tid = threadIdx.x;
  #pragma unroll
  for(int i=0;i<4;i++){
    int idx = tid + 256*i; int kl = idx>>5, nl = idx&31;
    int k = k0+kl, n = n0+nl;
    float v;
    if(n < 512)      v = wq[blk*512*512 + k*512 + n];
    else if(n < 640) v = wk[blk*512*128 + k*128 + (n-512)];
    else             v = wv[blk*512*128 + k*128 + (n-640)];
    tile[kl][nl] = v * ns[blk*512 + k];
  }
  __syncthreads();
  #pragma unroll
  for(int i=0;i<4;i++){
    int idx = tid + 256*i; int nl = idx>>5, kl = idx&31;
    wqkvt[blk*768*512 + (n0+nl)*512 + k0+kl] = f2u(tile[kl][nl]);
  }
}

// ---------------- persistent LSTM scan: all 63 steps in one launch (r3 structure + 2 deltas) ----------------
// 256 blocks x 256 thr (1 block/CU, 136 KB LDS). Block = (row group g: 64 rows) x (jj tile y: 32 jj x 4 gates).
// Bulk 16-producer barrier per step: tid==0 PREFETCHES the 4x16B flag snapshot at step start and
// checks after the wi-phase (poll RT hidden in steady state). Producers: epilogue -> dbuf LDS stage
// -> one coalesced 16B sc1 store/thread -> PER-WAVE vmcnt drain + per-wave flag byte (no drain barrier).
// wh (k 256..767) fully LDS-resident, XOR-swizzled; wi B-frags in regs; c-state in regs.
// MFMA order bit-identical to the round-3 passing kernel.
__global__ void __launch_bounds__(256,1) k_lstm_scan(
    const ushort* __restrict__ x, ushort* __restrict__ hs,
    const ushort* __restrict__ wt, const float* __restrict__ bias,
    uchar* __restrict__ flags)
{
  __shared__ __align__(16) short Bwh[128*512];        // 128 KB: wh k 256..767, row c = gate*32+jjl, swizzled
  __shared__ __align__(16) ushort hstage[2][64*32];   // 2 x 4 KB h staging (dbuf kills cross-step WAR)
  int fb = blockIdx.x;
  // XCD-grouping heuristic: members of a barrier group share blockIdx%8 -> same XCD
  int g = (fb & 7) | ((fb >> 4) & 8);
  int y = (fb >> 3) & 15;
  int n0 = g*64, jj0 = y*32;
  int tid = threadIdx.x;
  int wv = tid>>6, lane = tid&63, quad = lane>>4, l16 = lane&15;
  int wrow = wv>>1, wcol = wv&1;

  // fill Bwh: 128 c-rows x 64 short8 (k 256..767), 16B-block XOR swizzle by (c&7)
  for(int i=tid; i<8192; i+=256){
    int c = i>>6, kb = i&63;
    short8 v = *(const short8*)(wt + ((c>>5)*512 + jj0 + (c&31))*768 + 256 + kb*8);
    *(short8*)((char*)Bwh + c*1024 + ((kb*16) ^ ((c&7)<<4))) = v;
  }
  // wi B-fragments -> regs (4 gates x 8 k-chunks)
  int jj = jj0 + wcol*16 + l16;
  short8 bwi[4][8];
  #pragma unroll
  for(int gg=0; gg<4; gg++){
    const ushort* wp = wt + (gg*512 + jj)*768 + quad*8;
    #pragma unroll
    for(int ck=0; ck<8; ck++) bwi[gg][ck] = *(const short8*)(wp + ck*32);
  }
  float bI=bias[jj], bF=bias[512+jj], bG=bias[1024+jj], bO=bias[1536+jj];
  float cs[2][4];
  #pragma unroll
  for(int a=0;a<2;a++){
    #pragma unroll
    for(int r=0;r<4;r++) cs[a][r]=0.f;
  }
  const ushort* xb0 = x  + (n0 + wrow*32 + l16)*(NP*256) + quad*8;
  const ushort* hb0 = hs + (n0 + wrow*32 + l16)*(NP*512) + quad*8;
  int xorb = (l16&7)<<4;
  const uchar* gflags = flags + g*64;
  uchar* myflag = flags + g*64 + y*4 + wv;
  // coalesced-store (reader) params
  int srow = tid>>2, sc16 = tid&3;
  int soff = srow*64 + ((sc16*16) ^ (((srow>>2)&3)<<4));
  ushort* gpb = hs + (size_t)(n0+srow)*(NP*512) + jj0 + sc16*8;
  __syncthreads();   // Bwh ready

  for(int t=0; t<NP; ++t){
    i32x4 f0, f1, f2, f3;
    if(t>0 && tid==0){
      // prefetch flag snapshot (4x16B, sc1); consumed after the wi-phase
      asm volatile("global_load_dwordx4 %0, %1, off sc0 sc1" : "=&v"(f0) : "v"(gflags)    );
      asm volatile("global_load_dwordx4 %0, %1, off sc0 sc1" : "=&v"(f1) : "v"(gflags+16) );
      asm volatile("global_load_dwordx4 %0, %1, off sc0 sc1" : "=&v"(f2) : "v"(gflags+32) );
      asm volatile("global_load_dwordx4 %0, %1, off sc0 sc1" : "=&v"(f3) : "v"(gflags+48) );
    }

    f32x4 acc[4][2];
    #pragma unroll
    for(int gg=0; gg<4; gg++){ acc[gg][0]=(f32x4){0.f,0.f,0.f,0.f}; acc[gg][1]=(f32x4){0.f,0.f,0.f,0.f}; }

    // ---- x_t @ wi (k 0..255) — no recurrent dep, hides the snapshot latency ----
    #pragma unroll
    for(int ck=0; ck<8; ck++){
      short8 a0 = *(const short8*)(xb0 + t*256 + ck*32);
      short8 a1 = *(const short8*)(xb0 + 16*(NP*256) + t*256 + ck*32);
      #pragma unroll
      for(int gg=0; gg<4; gg++){
        acc[gg][0] = __builtin_amdgcn_mfma_f32_16x16x32_bf16(a0, bwi[gg][ck], acc[gg][0], 0,0,0);
        acc[gg][1] = __builtin_amdgcn_mfma_f32_16x16x32_bf16(a1, bwi[gg][ck], acc[gg][1], 0,0,0);
      }
    }

    if(t > 0){
      // ---- bulk group barrier: all 16 producers' 4 wave-bytes >= t ----
      if(tid==0){
        uint tag = (uint)t;
        asm volatile("s_waitcnt vmcnt(0)" : "+v"(f0), "+v"(f1), "+v"(f2), "+v"(f3) :: "memory");
        bool ok = bytes_ok((uint)f0[0],tag) && bytes_ok((uint)f0[1],tag) &&
                  bytes_ok((uint)f0[2],tag) && bytes_ok((uint)f0[3],tag) &&
                  bytes_ok((uint)f1[0],tag) && bytes_ok((uint)f1[1],tag) &&
                  bytes_ok((uint)f1[2],tag) && bytes_ok((uint)f1[3],tag) &&
                  bytes_ok((uint)f2[0],tag) && bytes_ok((uint)f2[1],tag) &&
                  bytes_ok((uint)f2[2],tag) && bytes_ok((uint)f2[3],tag) &&
                  bytes_ok((uint)f3[0],tag) && bytes_ok((uint)f3[1],tag) &&
                  bytes_ok((uint)f3[2],tag) && bytes_ok((uint)f3[3],tag);
        while(!ok){
          __builtin_amdgcn_s_sleep(1);
          asm volatile("global_load_dwordx4 %0, %4, off sc0 sc1\n\t"
                       "global_load_dwordx4 %1, %5, off sc0 sc1\n\t"
                       "global_load_dwordx4 %2, %6, off sc0 sc1\n\t"
                       "global_load_dwordx4 %3, %7, off sc0 sc1\n\t"
                       "s_waitcnt vmcnt(0)"
                       : "=&v"(f0), "=&v"(f1), "=&v"(f2), "=&v"(f3)
                       : "v"(gflags), "v"(gflags+16), "v"(gflags+32), "v"(gflags+48)
                       : "memory");
          ok = bytes_ok((uint)f0[0],tag) && bytes_ok((uint)f0[1],tag) &&
               bytes_ok((uint)f0[2],tag) && bytes_ok((uint)f0[3],tag) &&
               bytes_ok((uint)f1[0],tag) && bytes_ok((uint)f1[1],tag) &&
               bytes_ok((uint)f1[2],tag) && bytes_ok((uint)f1[3],tag) &&
               bytes_ok((uint)f2[0],tag) && bytes_ok((uint)f2[1],tag) &&
               bytes_ok((uint)f2[2],tag) && bytes_ok((uint)f2[3],tag) &&
               bytes_ok((uint)f3[0],tag) && bytes_ok((uint)f3[1],tag) &&
               bytes_ok((uint)f3[2],tag) && bytes_ok((uint)f3[3],tag);
        }
      }
      __syncthreads();   // gates all threads on tid==0's confirmation

      const ushort* hb = hb0 + (t-1)*512;
      // ---- h @ wh, k 256..767 entirely from LDS ----
      #pragma unroll
      for(int ck=0; ck<16; ck++){
        short8 a0 = *(const short8*)(hb + ck*32);
        short8 a1 = *(const short8*)(hb + 16*(NP*512) + ck*32);
        #pragma unroll
        for(int gg=0; gg<4; gg++){
          int c = gg*32 + wcol*16 + l16;
          short8 bh = *(short8*)((char*)Bwh + c*1024 + ((ck*64 + quad*16) ^ xorb));
          acc[gg][0] = __builtin_amdgcn_mfma_f32_16x16x32_bf16(a0, bh, acc[gg][0], 0,0,0);
          acc[gg][1] = __builtin_amdgcn_mfma_f32_16x16x32_bf16(a1, bh, acc[gg][1], 0,0,0);
        }
      }
    }

    // ---- gates + c-state (regs) + h -> LDS staging (dbuf, swizzled) ----
    ushort* hst = hstage[t&1];
    #pragma unroll
    for(int a=0;a<2;a++){
      #pragma unroll
      for(int r=0;r<4;r++){
        int rowl = wrow*32 + a*16 + quad*4 + r;
        float zi=acc[0][a][r]+bI, zf=acc[1][a][r]+bF, zg=acc[2][a][r]+bG, zo=acc[3][a][r]+bO;
        float c = sigf(zf)*cs[a][r] + sigf(zi)*tanhf(zg);
        cs[a][r] = c;
        float hv = sigf(zo)*tanhf(c);
        int coll = wcol*16 + l16;
        int off = rowl*64 + ((coll*2) ^ (((rowl>>2)&3)<<4));
        *(ushort*)((char*)hst + off) = f2u(hv);
      }
    }
    __syncthreads();   // stage complete
    // ---- coalesced device-visible h store: 256 threads x 16B; per-wave drain + flag ----
    {
      i32x4 vv = *(const i32x4*)((const char*)hst + soff);
      ushort* gp = gpb + (size_t)t*512;
      asm volatile("global_store_dwordx4 %0, %1, off sc0 sc1" :: "v"(gp), "v"(vv) : "memory");
    }
    if(t < NP-1){
      asm volatile("s_waitcnt vmcnt(0)" ::: "memory");
      uint tv = (uint)(t+1);
      asm volatile("global_store_byte %0, %1, off sc0 sc1" :: "v"(myflag), "v"(tv) : "memory");
    }
  }
}

// ---------------- rms_inv over H2=512 for attention rows ----------------
__global__ void __launch_bounds__(256) k_rms(const ushort* __restrict__ hs, float* __restrict__ rmsi)
{
  int tid = threadIdx.x;
  int r = blockIdx.x*4 + (tid>>6);
  int lane = tid&63;
  int bq = r/8064; int rr = r - bq*8064;
  int m = rr/1008; int rem = rr - m*1008;
  int p = rem>>4; int d = rem&15;
  int n = (bq*16+d)*8+m;
  const ushort* hp = hs + (n*NP+p)*512;
  float s=0.f;
  for(int c=lane;c<512;c+=64){ float v=u2f(hp[c]); s += v*v; }
  #pragma unroll
  for(int off=32;off>0;off>>=1) s += __shfl_down(s,off);
  if(lane==0) rmsi[r] = rsqrtf(s*(1.f/512.f)+1e-6f);
}

// ---------------- qkv GEMM via MFMA: 64512 x 768, K=512; rms applied on output ----------------
__global__ void __launch_bounds__(256) k_qkv_m(
    const ushort* __restrict__ hs, const float* __restrict__ rmsi,
    const ushort* __restrict__ wqkvt, ushort* __restrict__ qkv)
{
  __shared__ short As[64*40];
  __shared__ short Bs[128*40];
  int tid = threadIdx.x;
  int r0 = blockIdx.x*64, c0 = blockIdx.y*128;
  int wv = tid>>6, lane = tid&63, quad = lane>>4, l16 = lane&15;
  int arow = tid>>2, akp = tid&3;
  int r = r0 + arow;
  int bq = r/8064; int rr = r - bq*8064;
  int m = rr/1008; int rem = rr - m*1008;
  int p = rem>>4; int d = rem&15;
  int n = (bq*16+d)*8+m;
  const ushort* aptr = hs + (n*NP+p)*512 + akp*8;
  f32x4 acc[2][4];
  #pragma unroll
  for(int b=0;b<2;b++){
    #pragma unroll
    for(int a=0;a<4;a++) acc[b][a] = (f32x4){0.f,0.f,0.f,0.f};
  }
  for(int k0=0;k0<512;k0+=32){
    *(short8*)&As[arow*40+akp*8] = *(const short8*)(aptr + k0);
    #pragma unroll
    for(int i=0;i<2;i++){
      int pc = tid + 256*i; int rl=pc>>2, kp=pc&3;
      *(short8*)&Bs[rl*40+kp*8] = *(const short8*)(wqkvt + (c0+rl)*512 + k0 + kp*8);
    }
    __syncthreads();
    short8 af[4], bfr[2];
    #pragma unroll
    for(int a=0;a<4;a++) af[a] = *(short8*)&As[(a*16+l16)*40 + quad*8];
    #pragma unroll
    for(int b=0;b<2;b++) bfr[b] = *(short8*)&Bs[(wv*32+b*16+l16)*40 + quad*8];
    #pragma unroll
    for(int b=0;b<2;b++){
      #pragma unroll
      for(int a=0;a<4;a++)
        acc[b][a] = __builtin_amdgcn_mfma_f32_16x16x32_bf16(af[a], bfr[b], acc[b][a], 0,0,0);
    }
    __syncthreads();
  }
  #pragma unroll
  for(int a=0;a<4;a++){
    #pragma unroll
    for(int rg=0;rg<4;rg++){
      int rw = r0 + a*16 + quad*4 + rg;
      float rv = rmsi[rw];
      #pragma unroll
      for(int b=0;b<2;b++){
        int c = c0 + wv*32 + b*16 + l16;
        qkv[rw*768 + c] = f2u(acc[b][a][rg] * rv);
      }
    }
  }
}

// ---------------- attention (bf16 qkv buffer): per (row16-group, head) ----------------
__global__ void __launch_bounds__(256) k_attn(ushort* __restrict__ qkv)
{
  int r3 = blockIdx.x, h = blockIdx.y;
  int tid = threadIdx.x;
  __shared__ float qs[16][64];
  __shared__ float ks[16][65];
  __shared__ float vs[16][64];
  __shared__ float P[16][17];
  ushort* base = qkv + r3*16*768;
  int xx = tid&63, s4 = tid>>6;
  int kvh = (h>>2)*64;
  #pragma unroll
  for(int a=0;a<4;a++){
    int s = s4 + 4*a;
    qs[s][xx] = u2f(base[s*768 + h*64 + xx]);
    ks[s][xx] = u2f(base[s*768 + 512 + kvh + xx]);
    vs[s][xx] = u2f(base[s*768 + 640 + kvh + xx]);
  }
  __syncthreads();
  int i = tid>>4, j = tid&15;
  float sc = 0.f;
  #pragma unroll
  for(int xq=0;xq<64;xq++) sc = fmaf(qs[i][xq], ks[j][xq], sc);
  P[i][j] = sc*0.125f;
  __syncthreads();
  float row[16];
  #pragma unroll
  for(int jj=0;jj<16;jj++) row[jj] = P[i][jj];
  float mx = row[0];
  #pragma unroll
  for(int jj=1;jj<16;jj++) mx = fmaxf(mx, row[jj]);
  float sum = 0.f;
  #pragma unroll
  for(int jj=0;jj<16;jj++) sum += expf(row[jj]-mx);
  float pme = expf(row[j]-mx)/sum;
  __syncthreads();
  P[i][j] = pme;
  __syncthreads();
  #pragma unroll
  for(int a=0;a<4;a++){
    int s = s4 + 4*a;
    float o = 0.f;
    #pragma unroll
    for(int jj=0;jj<16;jj++) o = fmaf(P[s][jj], vs[jj][xx], o);
    base[s*768 + h*64 + xx] = f2u(o);
  }
}

// ---------------- bel GEMM via MFMA: O(64512x512 in qkv) @ wodt^T -> scatter bf16 xbuf ----------------
__global__ void __launch_bounds__(256) k_bel_m(
    const ushort* __restrict__ qkv, const ushort* __restrict__ wodt,
    ushort* __restrict__ x)
{
  __shared__ short As[64*40];
  __shared__ short Bs[128*40];
  int tid = threadIdx.x;
  int r0 = blockIdx.x*64, c0 = blockIdx.y*128;
  int wv = tid>>6, lane = tid&63, quad = lane>>4, l16 = lane&15;
  int arow = tid>>2, akp = tid&3;
  const ushort* aptr = qkv + (r0+arow)*768 + akp*8;
  f32x4 acc[2][4];
  #pragma unroll
  for(int b=0;b<2;b++){
    #pragma unroll
    for(int a=0;a<4;a++) acc[b][a] = (f32x4){0.f,0.f,0.f,0.f};
  }
  for(int k0=0;k0<512;k0+=32){
    *(short8*)&As[arow*40+akp*8] = *(const short8*)(aptr + k0);
    #pragma unroll
    for(int i=0;i<2;i++){
      int pc = tid + 256*i; int rl=pc>>2, kp=pc&3;
      *(short8*)&Bs[rl*40+kp*8] = *(const short8*)(wodt + (c0+rl)*512 + k0 + kp*8);
    }
    __syncthreads();
    short8 af[4], bfr[2];
    #pragma unroll
    for(int a=0;a<4;a++) af[a] = *(short8*)&As[(a*16+l16)*40 + quad*8];
    #pragma unroll
    for(int b=0;b<2;b++) bfr[b] = *(short8*)&Bs[(wv*32+b*16+l16)*40 + quad*8];
    #pragma unroll
    for(int b=0;b<2;b++){
      #pragma unroll
      for(int a=0;a<4;a++)
        acc[b][a] = __builtin_amdgcn_mfma_f32_16x16x32_bf16(af[a], bfr[b], acc[b][a], 0,0,0);
    }
    __syncthreads();
  }
  #pragma unroll
  for(int a=0;a<4;a++){
    #pragma unroll
    for(int rg=0;rg<4;rg++){
      int rw = r0 + a*16 + quad*4 + rg;
      int bq = rw/8064; int rr = rw - bq*8064;
      int m = rr/1008; int rem = rr - m*1008;
      int p = rem>>4; int d = rem&15;
      int n = (bq*16+d)*8+m;
      ushort* xo = x + (n*NP+p)*256;
      #pragma unroll
      for(int b=0;b<2;b++){
        int c = c0 + wv*32 + b*16 + l16;
        xo[c] = f2u(acc[b][a][rg]);
      }
    }
  }
}

// ---------------- head ----------------
__global__ void __launch_bounds__(256) k_head(const ushort* __restrict__ x,
    const float* __restrict__ meanv, const float* __restrict__ stdv,
    const float* __restrict__ rs, const float* __restrict__ rb,
    const float* __restrict__ hns, const float* __restrict__ pw,
    const float* __restrict__ qw, float* __restrict__ out)
{
  int n = blockIdx.x, tid = threadIdx.x;
  __shared__ float nb[256];
  __shared__ float red[256];
  float v = u2f(x[(n*NP + 62)*256 + tid]);
  red[tid] = v*v; __syncthreads();
  for(int s=128;s>0;s>>=1){
    if(tid<s) red[tid]+=red[tid+s];
    __syncthreads();
  }
  float rinv = rsqrtf(red[0]*(1.f/256.f)+1e-6f);
  nb[tid] = v*rinv*hns[tid];
  __syncthreads();
  int m = n&7;
  float mu=meanv[n], sd=stdv[n], sc=rs[m], bi=rb[m];
  for(int col=tid; col<384; col+=256){
    float acc=0.f;
    int slot, hh;
    if(col < 96){
      for(int k=0;k<256;k++) acc = fmaf(nb[k], pw[k*96+col], acc);
      slot = 0; hh = col;
    } else {
      int cq = col-96;
      for(int k=0;k<256;k++) acc = fmaf(nb[k], qw[k*288+cq], acc);
      int qi = cq - (cq/3)*3;
      slot = 1 + qi; hh = cq/3;
    }
    float y = (acc - bi)/sc*sd + mu;
    out[(slot*1024 + n)*96 + hh] = y;
  }
}

extern "C" void kernel_launch(void* const* d_in, const int* in_sizes, int n_in,
                              void* d_out, int out_size, void* d_ws, size_t ws_size,
                              hipStream_t stream)
{
  const float* series    = (const float*)d_in[0];
  const float* rs        = (const float*)d_in[1];
  const float* rb        = (const float*)d_in[2];
  const float* up_w      = (const float*)d_in[3];
  const float* lstm_wi   = (const float*)d_in[4];
  const float* lstm_wh   = (const float*)d_in[5];
  const float* lstm_b    = (const float*)d_in[6];
  const float* norm_scale= (const float*)d_in[7];
  const float* wq        = (const float*)d_in[8];
  const float* wk        = (const float*)d_in[9];
  const float* wv        = (const float*)d_in[10];
  const float* wo        = (const float*)d_in[11];
  const float* down_w    = (const float*)d_in[12];
  const float* head_ns   = (const float*)d_in[13];
  const float* point_w   = (const float*)d_in[14];
  const float* quant_w   = (const float*)d_in[15];
  float* out = (float*)d_out;

  float* ws = (float*)d_ws;
  float*  meanv = ws;                       // 1024
  float*  stdv  = meanv + 1024;             // 1024
  float*  rmsi  = stdv  + 1024;             // 64512
  float*  cst   = rmsi  + 64512;            // 524288 (c-state in regs; start reused for flag bytes)
  float*  wodf  = cst   + 524288;           // 524288
  ushort* xbuf  = (ushort*)(wodf + 524288);         // 16515072 bf16
  ushort* hsb   = xbuf  + 16515072;                 // 33030144 bf16
  ushort* qkvb  = hsb   + 33030144;                 // 49545216 bf16
  ushort* wt    = qkvb  + 49545216;                 // 6291456 bf16
  ushort* wqkvt = wt    + 6291456;                  // 1572864 bf16
  ushort* wodt  = wqkvt + 1572864;                  // 524288 bf16
  uchar*  flagb = (uchar*)cst;                      // 4 layers x 16 groups x 64 flag bytes

  k_revin<<<1024,256,0,stream>>>(series, meanv, stdv, (int*)flagb);
  k_patch<<<1024,256,0,stream>>>(series, rs, rb, up_w, meanv, stdv, xbuf);
  k_wod<<<dim3(512,4),256,0,stream>>>(wo, down_w, wodf);
  k_tr_wodt<<<dim3(8,16,4),256,0,stream>>>(wodf, wodt);
  k_tr_lstmw<<<dim3(64,24,4),256,0,stream>>>(lstm_wi, lstm_wh, wt);
  k_tr_qkvw<<<dim3(24,16,4),256,0,stream>>>(wq, wk, wv, norm_scale, wqkvt);

  for(int blk=0; blk<4; blk++){
    const ushort* wt_b = wt + blk*2048*768;
    const float*  bb   = lstm_b + blk*2048;
    k_lstm_scan<<<256,256,0,stream>>>(xbuf, hsb, wt_b, bb, flagb + blk*1024);
    k_rms<<<16128,256,0,stream>>>(hsb, rmsi);
    k_qkv_m<<<dim3(1008,6),256,0,stream>>>(hsb, rmsi, wqkvt + blk*768*512, qkvb);
    k_attn<<<dim3(4032,8),256,0,stream>>>(qkvb);
    k_bel_m<<<dim3(1008,2),256,0,stream>>>(qkvb, wodt + blk*256*512, xbuf);
  }
  k_head<<<1024,256,0,stream>>>(xbuf, meanv, stdv, rs, rb, head_ns, point_w, quant_w, out);
}

// Round 7
// 3708.676 us; speedup vs baseline: 1.5959x; 1.1733x over previous
//
#include <hip/hip_runtime.h>
#include <hip/hip_bf16.h>

#define NP 63   // number of patches

typedef __attribute__((ext_vector_type(8))) short short8;
typedef __attribute__((ext_vector_type(4))) float f32x4;
typedef __attribute__((ext_vector_type(4))) int i32x4;
typedef unsigned char uchar;

__device__ __forceinline__ float sigf(float x){ return 1.0f/(1.0f+expf(-x)); }
__device__ __forceinline__ float u2f(ushort u){ __hip_bfloat16 h; *(ushort*)&h = u; return __bfloat162float(h); }
__device__ __forceinline__ ushort f2u(float f){ __hip_bfloat16 h = __float2bfloat16(f); return *(ushort*)&h; }

// ---------------- RevIN stats (+ zero persistent-scan flag bytes) ----------------
__global__ void __launch_bounds__(256) k_revin(const float* __restrict__ series,
    float* __restrict__ meanv, float* __restrict__ stdv, int* __restrict__ bar)
{
  int n = blockIdx.x, tid = threadIdx.x;
  if(n==0 && tid<64) bar[tid] = 0;   // 256 flag bytes (16 groups x 16 blocks)
  __shared__ float s1[256], s2[256];
  const float* p = series + n*512;
  float a = 0.f, b = 0.f;
  for(int t=tid;t<512;t+=256){ float v=p[t]; a+=v; b+=v*v; }
  s1[tid]=a; s2[tid]=b; __syncthreads();
  for(int s=128;s>0;s>>=1){
    if(tid<s){ s1[tid]+=s1[tid+s]; s2[tid]+=s2[tid+s]; }
    __syncthreads();
  }
  if(tid==0){
    float mu = s1[0]*(1.f/512.f);
    float var = fmaxf(s2[0]*(1.f/512.f) - mu*mu, 0.f);
    meanv[n]=mu; stdv[n]=sqrtf(var+1e-5f);
  }
}

// ---------------- patch embed -> bf16 xbuf ----------------
__global__ void __launch_bounds__(256) k_patch(const float* __restrict__ series,
    const float* __restrict__ rs, const float* __restrict__ rb,
    const float* __restrict__ up_w, const float* __restrict__ meanv,
    const float* __restrict__ stdv, ushort* __restrict__ x)
{
  int n = blockIdx.x, tid = threadIdx.x;
  int m = n & 7;
  __shared__ float sn[512];
  float mu = meanv[n], sd = stdv[n];
  float A = rs[m]/sd, C = rb[m] - mu*A;
  const float* p = series + n*512;
  for(int t=tid;t<512;t+=256) sn[t] = p[t]*A + C;
  __syncthreads();
  float w[16];
  #pragma unroll
  for(int i=0;i<16;i++) w[i] = up_w[i*256+tid];
  ushort* xo = x + n*(NP*256);
  for(int pi=0;pi<NP;pi++){
    float acc=0.f;
    #pragma unroll
    for(int i=0;i<16;i++) acc = fmaf(sn[pi*8+i], w[i], acc);
    xo[pi*256+tid] = f2u(acc);
  }
}

// ---------------- W_od = wo @ down_w (f32) ----------------
__global__ void __launch_bounds__(256) k_wod(const float* __restrict__ wo,
    const float* __restrict__ dw, float* __restrict__ wod)
{
  int i = blockIdx.x, blk = blockIdx.y, tid = threadIdx.x;
  __shared__ float row[512];
  const float* wr = wo + (blk*512 + i)*512;
  for(int k=tid;k<512;k+=256) row[k]=wr[k];
  __syncthreads();
  const float* d = dw + blk*512*256;
  float acc=0.f;
  for(int k=0;k<512;k++) acc = fmaf(row[k], d[k*256+tid], acc);
  wod[(blk*512+i)*256+tid]=acc;
}

// ---------------- transpose wod (512k x 256n) -> wodt bf16 [256][512] ----------------
__global__ void __launch_bounds__(256) k_tr_wodt(const float* __restrict__ wod, ushort* __restrict__ wodt)
{
  __shared__ float tile[32][33];
  int blk = blockIdx.z;
  int n0 = blockIdx.x*32, k0 = blockIdx.y*32;
  int tid = threadIdx.x;
  #pragma unroll
  for(int i=0;i<4;i++){
    int idx = tid + 256*i; int kl = idx>>5, nl = idx&31;
    tile[kl][nl] = wod[blk*512*256 + (k0+kl)*256 + n0+nl];
  }
  __syncthreads();
  #pragma unroll
  for(int i=0;i<4;i++){
    int idx = tid + 256*i; int nl = idx>>5, kl = idx&31;
    wodt[blk*256*512 + (n0+nl)*512 + k0+kl] = f2u(tile[kl][nl]);
  }
}

// ---------------- transpose [wi;wh] (768k x 2048n) -> wt bf16 [2048][768] ----------------
__global__ void __launch_bounds__(256) k_tr_lstmw(const float* __restrict__ wi,
    const float* __restrict__ wh, ushort* __restrict__ wt)
{
  __shared__ float tile[32][33];
  int blk = blockIdx.z;
  int n0 = blockIdx.x*32, k0 = blockIdx.y*32;
  int tid = threadIdx.x;
  #pragma unroll
  for(int i=0;i<4;i++){
    int idx = tid + 256*i; int kl = idx>>5, nl = idx&31;
    int k = k0+kl, n = n0+nl;
    float v = (k<256) ? wi[blk*256*2048 + k*2048 + n]
                      : wh[blk*512*2048 + (k-256)*2048 + n];
    tile[kl][nl] = v;
  }
  __syncthreads();
  #pragma unroll
  for(int i=0;i<4;i++){
    int idx = tid + 256*i; int nl = idx>>5, kl = idx&31;
    wt[blk*2048*768 + (n0+nl)*768 + k0+kl] = f2u(tile[kl][nl]);
  }
}

// ---------------- transpose [wq|wk|wv] (512k x 768n), fold ns[k] -> wqkvt bf16 [768][512] ----------------
__global__ void __launch_bounds__(256) k_tr_qkvw(const float* __restrict__ wq,
    const float* __restrict__ wk, const float* __restrict__ wv,
    const float* __restrict__ ns, ushort* __restrict__ wqkvt)
{
  __shared__ float tile[32][33];
  int blk = blockIdx.z;
  int n0 = blockIdx.x*32, k0 = blockIdx.y*32;
  int tid = threadIdx.x;
  #pragma unroll
  for(int i=0;i<4;i++){
    int idx = tid + 256*i; int kl = idx>>5, nl = idx&31;
    int k = k0+kl, n = n0+nl;
    float v;
    if(n < 512)      v = wq[blk*512*512 + k*512 + n];
    else if(n < 640) v = wk[blk*512*128 + k*128 + (n-512)];
    else             v = wv[blk*512*128 + k*128 + (n-640)];
    tile[kl][nl] = v * ns[blk*512 + k];
  }
  __syncthreads();
  #pragma unroll
  for(int i=0;i<4;i++){
    int idx = tid + 256*i; int nl = idx>>5, kl = idx&31;
    wqkvt[blk*768*512 + (n0+nl)*512 + k0+kl] = f2u(tile[kl][nl]);
  }
}

// ---------------- persistent LSTM scan: all 63 steps in one launch (r3-verified structure) ----------------
// 256 blocks x 256 thr, 1 block/CU (132 KB LDS). Block = (row group g: 64 rows) x (jj tile y: 32 jj x 4 gates).
// Cross-block dep row-local: 16-block group barrier per step via BYTE FLAGS in one 16B line
// (monotonic tag = tagbase+t+1; poll = one sc1 dwordx4 load + 16 byte >= compares; no RMW).
// h stores coalesced: epilogue -> LDS staging tile -> one 16B sc1 store/thread.
// wi B-frags in regs; wh (k 256..767) fully LDS-resident, XOR-swizzled. c-state in regs.
__global__ void __launch_bounds__(256,1) k_lstm_scan(
    const ushort* __restrict__ x, ushort* __restrict__ hs,
    const ushort* __restrict__ wt, const float* __restrict__ bias,
    uchar* __restrict__ flags, int tagbase)
{
  __shared__ __align__(16) short Bwh[128*512];     // 128 KB: c row (gate*32+jjl) x k 256..767, swizzled
  __shared__ __align__(16) ushort hstage[64*32];   // 4 KB h staging
  int fb = blockIdx.x;
  // XCD-grouping heuristic: members of a barrier group share blockIdx%8 -> same XCD
  int g = (fb & 7) | ((fb >> 4) & 8);
  int y = (fb >> 3) & 15;
  int n0 = g*64, jj0 = y*32;
  int tid = threadIdx.x;
  int wv = tid>>6, lane = tid&63, quad = lane>>4, l16 = lane&15;
  int wrow = wv>>1, wcol = wv&1;

  // fill Bwh: 128 c-rows x 64 short8 (k 256..767), 16B-block XOR swizzle by (c&7)
  for(int i=tid; i<8192; i+=256){
    int c = i>>6, kb = i&63;
    short8 v = *(const short8*)(wt + ((c>>5)*512 + jj0 + (c&31))*768 + 256 + kb*8);
    *(short8*)((char*)Bwh + c*1024 + ((kb*16) ^ ((c&7)<<4))) = v;
  }
  // wi B-fragments -> regs (4 gates x 8 k-chunks)
  int jj = jj0 + wcol*16 + l16;
  short8 bwi[4][8];
  #pragma unroll
  for(int gg=0; gg<4; gg++){
    const ushort* wp = wt + (gg*512 + jj)*768 + quad*8;
    #pragma unroll
    for(int ck=0; ck<8; ck++) bwi[gg][ck] = *(const short8*)(wp + ck*32);
  }
  float bI=bias[jj], bF=bias[512+jj], bG=bias[1024+jj], bO=bias[1536+jj];
  float cs[2][4];
  #pragma unroll
  for(int a=0;a<2;a++){
    #pragma unroll
    for(int r=0;r<4;r++) cs[a][r]=0.f;
  }
  const ushort* xb0 = x  + (n0 + wrow*32 + l16)*(NP*256) + quad*8;
  const ushort* hb0 = hs + (n0 + wrow*32 + l16)*(NP*512) + quad*8;
  int xorb = (l16&7)<<4;
  uchar* myflag = flags + g*16 + y;
  const uchar* gflags = flags + g*16;
  __syncthreads();

  for(int t=0; t<NP; ++t){
    f32x4 acc[4][2];
    #pragma unroll
    for(int gg=0; gg<4; gg++){ acc[gg][0]=(f32x4){0.f,0.f,0.f,0.f}; acc[gg][1]=(f32x4){0.f,0.f,0.f,0.f}; }

    // ---- x_t @ wi (k 0..255) — no recurrent dep, runs before the group wait ----
    #pragma unroll
    for(int ck=0; ck<8; ck++){
      short8 a0 = *(const short8*)(xb0 + t*256 + ck*32);
      short8 a1 = *(const short8*)(xb0 + 16*(NP*256) + t*256 + ck*32);
      #pragma unroll
      for(int gg=0; gg<4; gg++){
        acc[gg][0] = __builtin_amdgcn_mfma_f32_16x16x32_bf16(a0, bwi[gg][ck], acc[gg][0], 0,0,0);
        acc[gg][1] = __builtin_amdgcn_mfma_f32_16x16x32_bf16(a1, bwi[gg][ck], acc[gg][1], 0,0,0);
      }
    }

    if(t > 0){
      // ---- group barrier: all 16 flag bytes >= tagbase+t (monotonic; '>=' tolerates fast blocks) ----
      if(tid==0){
        uint tag = (uint)(tagbase + t);
        while(1){
          i32x4 f;
          asm volatile("global_load_dwordx4 %0, %1, off sc0 sc1\n\ts_waitcnt vmcnt(0)"
                       : "=&v"(f) : "v"(gflags) : "memory");
          uint ok = 1u;
          #pragma unroll
          for(int q=0;q<4;q++){
            uint w = (uint)f[q];
            if(( w      &0xffu) < tag) ok=0;
            if(((w>>8 ) &0xffu) < tag) ok=0;
            if(((w>>16) &0xffu) < tag) ok=0;
            if( (w>>24)         < tag) ok=0;
          }
          if(ok) break;
          __builtin_amdgcn_s_sleep(1);
        }
      }
      __syncthreads();

      const ushort* hb = hb0 + (t-1)*512;
      // ---- h @ wh, k 256..767 entirely from LDS ----
      #pragma unroll
      for(int ck=0; ck<16; ck++){
        short8 a0 = *(const short8*)(hb + ck*32);
        short8 a1 = *(const short8*)(hb + 16*(NP*512) + ck*32);
        #pragma unroll
        for(int gg=0; gg<4; gg++){
          int c = gg*32 + wcol*16 + l16;
          short8 bh = *(short8*)((char*)Bwh + c*1024 + ((ck*64 + quad*16) ^ xorb));
          acc[gg][0] = __builtin_amdgcn_mfma_f32_16x16x32_bf16(a0, bh, acc[gg][0], 0,0,0);
          acc[gg][1] = __builtin_amdgcn_mfma_f32_16x16x32_bf16(a1, bh, acc[gg][1], 0,0,0);
        }
      }
    }

    // ---- gates + c-state (regs) + h -> LDS staging (swizzled) ----
    #pragma unroll
    for(int a=0;a<2;a++){
      #pragma unroll
      for(int r=0;r<4;r++){
        int rowl = wrow*32 + a*16 + quad*4 + r;
        float zi=acc[0][a][r]+bI, zf=acc[1][a][r]+bF, zg=acc[2][a][r]+bG, zo=acc[3][a][r]+bO;
        float c = sigf(zf)*cs[a][r] + sigf(zi)*tanhf(zg);
        cs[a][r] = c;
        float hv = sigf(zo)*tanhf(c);
        int coll = wcol*16 + l16;
        int off = rowl*64 + ((coll*2) ^ (((rowl>>2)&3)<<4));
        *(ushort*)((char*)hstage + off) = f2u(hv);
      }
    }
    __syncthreads();
    // ---- coalesced device-visible h store: 256 threads x 16B ----
    {
      int rowl = tid>>2, c0b = (tid&3)*16;
      int off = rowl*64 + (c0b ^ (((rowl>>2)&3)<<4));
      i32x4 vv = *(const i32x4*)((const char*)hstage + off);
      ushort* gp = hs + ((size_t)(n0+rowl)*NP + t)*512 + jj0 + (tid&3)*8;
      asm volatile("global_store_dwordx4 %0, %1, off sc0 sc1" :: "v"(gp), "v"(vv) : "memory");
    }
    __syncthreads();   // drains vmcnt(0) per wave -> all h stores at coherence point
    if(tid==0 && t < NP-1){
      uint v = (uint)(tagbase + t + 1);
      asm volatile("global_store_byte %0, %1, off sc0 sc1" :: "v"(myflag), "v"(v) : "memory");
    }
  }
}

// ---------------- qkv GEMM via MFMA: 64512 x 768, K=512; rms fused (computed during As staging) ----------------
// grid (1008, 6): block 64 rows x 128 cols, 4 waves split cols.
__global__ void __launch_bounds__(256) k_qkv_m(
    const ushort* __restrict__ hs, const ushort* __restrict__ wqkvt,
    ushort* __restrict__ qkv)
{
  __shared__ short As[64*40];
  __shared__ short Bs[128*40];
  __shared__ float rvs[64];
  int tid = threadIdx.x;
  int r0 = blockIdx.x*64, c0 = blockIdx.y*128;
  int wv = tid>>6, lane = tid&63, quad = lane>>4, l16 = lane&15;
  int arow = tid>>2, akp = tid&3;
  int r = r0 + arow;
  int bq = r/8064; int rr = r - bq*8064;
  int m = rr/1008; int rem = rr - m*1008;
  int p = rem>>4; int d = rem&15;
  int n = (bq*16+d)*8+m;
  const ushort* aptr = hs + (n*NP+p)*512 + akp*8;
  f32x4 acc[2][4];
  #pragma unroll
  for(int b=0;b<2;b++){
    #pragma unroll
    for(int a=0;a<4;a++) acc[b][a] = (f32x4){0.f,0.f,0.f,0.f};
  }
  float ssq = 0.f;   // fused rms: sum of squares of this thread's slice of row arow
  for(int k0=0;k0<512;k0+=32){
    short8 av = *(const short8*)(aptr + k0);
    *(short8*)&As[arow*40+akp*8] = av;
    #pragma unroll
    for(int e=0;e<8;e++){ float vv = u2f((ushort)av[e]); ssq = fmaf(vv, vv, ssq); }
    #pragma unroll
    for(int i=0;i<2;i++){
      int pc = tid + 256*i; int rl=pc>>2, kp=pc&3;
      *(short8*)&Bs[rl*40+kp*8] = *(const short8*)(wqkvt + (c0+rl)*512 + k0 + kp*8);
    }
    __syncthreads();
    short8 af[4], bfr[2];
    #pragma unroll
    for(int a=0;a<4;a++) af[a] = *(short8*)&As[(a*16+l16)*40 + quad*8];
    #pragma unroll
    for(int b=0;b<2;b++) bfr[b] = *(short8*)&Bs[(wv*32+b*16+l16)*40 + quad*8];
    #pragma unroll
    for(int b=0;b<2;b++){
      #pragma unroll
      for(int a=0;a<4;a++)
        acc[b][a] = __builtin_amdgcn_mfma_f32_16x16x32_bf16(af[a], bfr[b], acc[b][a], 0,0,0);
    }
    __syncthreads();
  }
  // reduce ssq across the 4 threads (akp 0..3) sharing row arow -> rvs[arow]
  ssq += __shfl_xor(ssq, 1);
  ssq += __shfl_xor(ssq, 2);
  if(akp==0) rvs[arow] = rsqrtf(ssq*(1.f/512.f)+1e-6f);
  __syncthreads();
  #pragma unroll
  for(int a=0;a<4;a++){
    #pragma unroll
    for(int rg=0;rg<4;rg++){
      int rowl = a*16 + quad*4 + rg;
      int rw = r0 + rowl;
      float rv = rvs[rowl];
      #pragma unroll
      for(int b=0;b<2;b++){
        int c = c0 + wv*32 + b*16 + l16;
        qkv[rw*768 + c] = f2u(acc[b][a][rg] * rv);
      }
    }
  }
}

// ---------------- attention (bf16 qkv buffer): per (row16-group, head) ----------------
__global__ void __launch_bounds__(256) k_attn(ushort* __restrict__ qkv)
{
  int r3 = blockIdx.x, h = blockIdx.y;
  int tid = threadIdx.x;
  __shared__ float qs[16][64];
  __shared__ float ks[16][65];
  __shared__ float vs[16][64];
  __shared__ float P[16][17];
  ushort* base = qkv + r3*16*768;
  int xx = tid&63, s4 = tid>>6;
  int kvh = (h>>2)*64;
  #pragma unroll
  for(int a=0;a<4;a++){
    int s = s4 + 4*a;
    qs[s][xx] = u2f(base[s*768 + h*64 + xx]);
    ks[s][xx] = u2f(base[s*768 + 512 + kvh + xx]);
    vs[s][xx] = u2f(base[s*768 + 640 + kvh + xx]);
  }
  __syncthreads();
  int i = tid>>4, j = tid&15;
  float sc = 0.f;
  #pragma unroll
  for(int xq=0;xq<64;xq++) sc = fmaf(qs[i][xq], ks[j][xq], sc);
  P[i][j] = sc*0.125f;
  __syncthreads();
  float row[16];
  #pragma unroll
  for(int jj=0;jj<16;jj++) row[jj] = P[i][jj];
  float mx = row[0];
  #pragma unroll
  for(int jj=1;jj<16;jj++) mx = fmaxf(mx, row[jj]);
  float sum = 0.f;
  #pragma unroll
  for(int jj=0;jj<16;jj++) sum += expf(row[jj]-mx);
  float pme = expf(row[j]-mx)/sum;
  __syncthreads();
  P[i][j] = pme;
  __syncthreads();
  #pragma unroll
  for(int a=0;a<4;a++){
    int s = s4 + 4*a;
    float o = 0.f;
    #pragma unroll
    for(int jj=0;jj<16;jj++) o = fmaf(P[s][jj], vs[jj][xx], o);
    base[s*768 + h*64 + xx] = f2u(o);
  }
}

// ---------------- bel GEMM via MFMA: O(64512x512 in qkv) @ wodt^T -> scatter bf16 xbuf ----------------
__global__ void __launch_bounds__(256) k_bel_m(
    const ushort* __restrict__ qkv, const ushort* __restrict__ wodt,
    ushort* __restrict__ x)
{
  __shared__ short As[64*40];
  __shared__ short Bs[128*40];
  int tid = threadIdx.x;
  int r0 = blockIdx.x*64, c0 = blockIdx.y*128;
  int wv = tid>>6, lane = tid&63, quad = lane>>4, l16 = lane&15;
  int arow = tid>>2, akp = tid&3;
  const ushort* aptr = qkv + (r0+arow)*768 + akp*8;
  f32x4 acc[2][4];
  #pragma unroll
  for(int b=0;b<2;b++){
    #pragma unroll
    for(int a=0;a<4;a++) acc[b][a] = (f32x4){0.f,0.f,0.f,0.f};
  }
  for(int k0=0;k0<512;k0+=32){
    *(short8*)&As[arow*40+akp*8] = *(const short8*)(aptr + k0);
    #pragma unroll
    for(int i=0;i<2;i++){
      int pc = tid + 256*i; int rl=pc>>2, kp=pc&3;
      *(short8*)&Bs[rl*40+kp*8] = *(const short8*)(wodt + (c0+rl)*512 + k0 + kp*8);
    }
    __syncthreads();
    short8 af[4], bfr[2];
    #pragma unroll
    for(int a=0;a<4;a++) af[a] = *(short8*)&As[(a*16+l16)*40 + quad*8];
    #pragma unroll
    for(int b=0;b<2;b++) bfr[b] = *(short8*)&Bs[(wv*32+b*16+l16)*40 + quad*8];
    #pragma unroll
    for(int b=0;b<2;b++){
      #pragma unroll
      for(int a=0;a<4;a++)
        acc[b][a] = __builtin_amdgcn_mfma_f32_16x16x32_bf16(af[a], bfr[b], acc[b][a], 0,0,0);
    }
    __syncthreads();
  }
  #pragma unroll
  for(int a=0;a<4;a++){
    #pragma unroll
    for(int rg=0;rg<4;rg++){
      int rw = r0 + a*16 + quad*4 + rg;
      int bq = rw/8064; int rr = rw - bq*8064;
      int m = rr/1008; int rem = rr - m*1008;
      int p = rem>>4; int d = rem&15;
      int n = (bq*16+d)*8+m;
      ushort* xo = x + (n*NP+p)*256;
      #pragma unroll
      for(int b=0;b<2;b++){
        int c = c0 + wv*32 + b*16 + l16;
        xo[c] = f2u(acc[b][a][rg]);
      }
    }
  }
}

// ---------------- head ----------------
__global__ void __launch_bounds__(256) k_head(const ushort* __restrict__ x,
    const float* __restrict__ meanv, const float* __restrict__ stdv,
    const float* __restrict__ rs, const float* __restrict__ rb,
    const float* __restrict__ hns, const float* __restrict__ pw,
    const float* __restrict__ qw, float* __restrict__ out)
{
  int n = blockIdx.x, tid = threadIdx.x;
  __shared__ float nb[256];
  __shared__ float red[256];
  float v = u2f(x[(n*NP + 62)*256 + tid]);
  red[tid] = v*v; __syncthreads();
  for(int s=128;s>0;s>>=1){
    if(tid<s) red[tid]+=red[tid+s];
    __syncthreads();
  }
  float rinv = rsqrtf(red[0]*(1.f/256.f)+1e-6f);
  nb[tid] = v*rinv*hns[tid];
  __syncthreads();
  int m = n&7;
  float mu=meanv[n], sd=stdv[n], sc=rs[m], bi=rb[m];
  for(int col=tid; col<384; col+=256){
    float acc=0.f;
    int slot, hh;
    if(col < 96){
      for(int k=0;k<256;k++) acc = fmaf(nb[k], pw[k*96+col], acc);
      slot = 0; hh = col;
    } else {
      int cq = col-96;
      for(int k=0;k<256;k++) acc = fmaf(nb[k], qw[k*288+cq], acc);
      int qi = cq - (cq/3)*3;
      slot = 1 + qi; hh = cq/3;
    }
    float y = (acc - bi)/sc*sd + mu;
    out[(slot*1024 + n)*96 + hh] = y;
  }
}

extern "C" void kernel_launch(void* const* d_in, const int* in_sizes, int n_in,
                              void* d_out, int out_size, void* d_ws, size_t ws_size,
                              hipStream_t stream)
{
  const float* series    = (const float*)d_in[0];
  const float* rs        = (const float*)d_in[1];
  const float* rb        = (const float*)d_in[2];
  const float* up_w      = (const float*)d_in[3];
  const float* lstm_wi   = (const float*)d_in[4];
  const float* lstm_wh   = (const float*)d_in[5];
  const float* lstm_b    = (const float*)d_in[6];
  const float* norm_scale= (const float*)d_in[7];
  const float* wq        = (const float*)d_in[8];
  const float* wk        = (const float*)d_in[9];
  const float* wv        = (const float*)d_in[10];
  const float* wo        = (const float*)d_in[11];
  const float* down_w    = (const float*)d_in[12];
  const float* head_ns   = (const float*)d_in[13];
  const float* point_w   = (const float*)d_in[14];
  const float* quant_w   = (const float*)d_in[15];
  float* out = (float*)d_out;

  float* ws = (float*)d_ws;
  float*  meanv = ws;                       // 1024
  float*  stdv  = meanv + 1024;             // 1024
  float*  rmsi  = stdv  + 1024;             // 64512 (unused now; kept for layout stability)
  float*  cst   = rmsi  + 64512;            // 524288 (c-state in regs; start reused for flag bytes)
  float*  wodf  = cst   + 524288;           // 524288
  ushort* xbuf  = (ushort*)(wodf + 524288);         // 16515072 bf16
  ushort* hsb   = xbuf  + 16515072;                 // 33030144 bf16
  ushort* qkvb  = hsb   + 33030144;                 // 49545216 bf16
  ushort* wt    = qkvb  + 49545216;                 // 6291456 bf16
  ushort* wqkvt = wt    + 6291456;                  // 1572864 bf16
  ushort* wodt  = wqkvt + 1572864;                  // 524288 bf16
  int*    bar   = (int*)cst;                        // 256 flag bytes (16 groups x 16 blocks)

  k_revin<<<1024,256,0,stream>>>(series, meanv, stdv, bar);
  k_patch<<<1024,256,0,stream>>>(series, rs, rb, up_w, meanv, stdv, xbuf);
  k_wod<<<dim3(512,4),256,0,stream>>>(wo, down_w, wodf);
  k_tr_wodt<<<dim3(8,16,4),256,0,stream>>>(wodf, wodt);
  k_tr_lstmw<<<dim3(64,24,4),256,0,stream>>>(lstm_wi, lstm_wh, wt);
  k_tr_qkvw<<<dim3(24,16,4),256,0,stream>>>(wq, wk, wv, norm_scale, wqkvt);

  for(int blk=0; blk<4; blk++){
    const ushort* wt_b = wt + blk*2048*768;
    const float*  bb   = lstm_b + blk*2048;
    k_lstm_scan<<<256,256,0,stream>>>(xbuf, hsb, wt_b, bb, (uchar*)bar, blk*NP);
    k_qkv_m<<<dim3(1008,6),256,0,stream>>>(hsb, wqkvt + blk*768*512, qkvb);
    k_attn<<<dim3(4032,8),256,0,stream>>>(qkvb);
    k_bel_m<<<dim3(1008,2),256,0,stream>>>(qkvb, wodt + blk*256*512, xbuf);
  }
  k_head<<<1024,256,0,stream>>>(xbuf, meanv, stdv, rs, rb, head_ns, point_w, quant_w, out);
}

// Round 8
// 3631.179 us; speedup vs baseline: 1.6299x; 1.0213x over previous
//
#include <hip/hip_runtime.h>
#include <hip/hip_bf16.h>

#define NP 63   // number of patches

typedef __attribute__((ext_vector_type(8))) short short8;
typedef __attribute__((ext_vector_type(4))) float f32x4;
typedef __attribute__((ext_vector_type(4))) int i32x4;
typedef unsigned char uchar;

__device__ __forceinline__ float sigf(float x){ return 1.0f/(1.0f+expf(-x)); }
__device__ __forceinline__ float u2f(ushort u){ __hip_bfloat16 h; *(ushort*)&h = u; return __bfloat162float(h); }
__device__ __forceinline__ ushort f2u(float f){ __hip_bfloat16 h = __float2bfloat16(f); return *(ushort*)&h; }

// ---------------- RevIN stats (+ zero persistent-scan flag bytes) ----------------
__global__ void __launch_bounds__(256) k_revin(const float* __restrict__ series,
    float* __restrict__ meanv, float* __restrict__ stdv, int* __restrict__ bar)
{
  int n = blockIdx.x, tid = threadIdx.x;
  if(n==0 && tid<64) bar[tid] = 0;   // 256 flag bytes (16 groups x 16 blocks)
  __shared__ float s1[256], s2[256];
  const float* p = series + n*512;
  float a = 0.f, b = 0.f;
  for(int t=tid;t<512;t+=256){ float v=p[t]; a+=v; b+=v*v; }
  s1[tid]=a; s2[tid]=b; __syncthreads();
  for(int s=128;s>0;s>>=1){
    if(tid<s){ s1[tid]+=s1[tid+s]; s2[tid]+=s2[tid+s]; }
    __syncthreads();
  }
  if(tid==0){
    float mu = s1[0]*(1.f/512.f);
    float var = fmaxf(s2[0]*(1.f/512.f) - mu*mu, 0.f);
    meanv[n]=mu; stdv[n]=sqrtf(var+1e-5f);
  }
}

// ---------------- patch embed -> bf16 xbuf ----------------
__global__ void __launch_bounds__(256) k_patch(const float* __restrict__ series,
    const float* __restrict__ rs, const float* __restrict__ rb,
    const float* __restrict__ up_w, const float* __restrict__ meanv,
    const float* __restrict__ stdv, ushort* __restrict__ x)
{
  int n = blockIdx.x, tid = threadIdx.x;
  int m = n & 7;
  __shared__ float sn[512];
  float mu = meanv[n], sd = stdv[n];
  float A = rs[m]/sd, C = rb[m] - mu*A;
  const float* p = series + n*512;
  for(int t=tid;t<512;t+=256) sn[t] = p[t]*A + C;
  __syncthreads();
  float w[16];
  #pragma unroll
  for(int i=0;i<16;i++) w[i] = up_w[i*256+tid];
  ushort* xo = x + n*(NP*256);
  for(int pi=0;pi<NP;pi++){
    float acc=0.f;
    #pragma unroll
    for(int i=0;i<16;i++) acc = fmaf(sn[pi*8+i], w[i], acc);
    xo[pi*256+tid] = f2u(acc);
  }
}

// ---------------- W_od = wo @ down_w (f32) ----------------
__global__ void __launch_bounds__(256) k_wod(const float* __restrict__ wo,
    const float* __restrict__ dw, float* __restrict__ wod)
{
  int i = blockIdx.x, blk = blockIdx.y, tid = threadIdx.x;
  __shared__ float row[512];
  const float* wr = wo + (blk*512 + i)*512;
  for(int k=tid;k<512;k+=256) row[k]=wr[k];
  __syncthreads();
  const float* d = dw + blk*512*256;
  float acc=0.f;
  for(int k=0;k<512;k++) acc = fmaf(row[k], d[k*256+tid], acc);
  wod[(blk*512+i)*256+tid]=acc;
}

// ---------------- transpose wod (512k x 256n) -> wodt bf16 [256][512] ----------------
__global__ void __launch_bounds__(256) k_tr_wodt(const float* __restrict__ wod, ushort* __restrict__ wodt)
{
  __shared__ float tile[32][33];
  int blk = blockIdx.z;
  int n0 = blockIdx.x*32, k0 = blockIdx.y*32;
  int tid = threadIdx.x;
  #pragma unroll
  for(int i=0;i<4;i++){
    int idx = tid + 256*i; int kl = idx>>5, nl = idx&31;
    tile[kl][nl] = wod[blk*512*256 + (k0+kl)*256 + n0+nl];
  }
  __syncthreads();
  #pragma unroll
  for(int i=0;i<4;i++){
    int idx = tid + 256*i; int nl = idx>>5, kl = idx&31;
    wodt[blk*256*512 + (n0+nl)*512 + k0+kl] = f2u(tile[kl][nl]);
  }
}

// ---------------- transpose [wi;wh] (768k x 2048n) -> wt bf16 [2048][768] ----------------
__global__ void __launch_bounds__(256) k_tr_lstmw(const float* __restrict__ wi,
    const float* __restrict__ wh, ushort* __restrict__ wt)
{
  __shared__ float tile[32][33];
  int blk = blockIdx.z;
  int n0 = blockIdx.x*32, k0 = blockIdx.y*32;
  int tid = threadIdx.x;
  #pragma unroll
  for(int i=0;i<4;i++){
    int idx = tid + 256*i; int kl = idx>>5, nl = idx&31;
    int k = k0+kl, n = n0+nl;
    float v = (k<256) ? wi[blk*256*2048 + k*2048 + n]
                      : wh[blk*512*2048 + (k-256)*2048 + n];
    tile[kl][nl] = v;
  }
  __syncthreads();
  #pragma unroll
  for(int i=0;i<4;i++){
    int idx = tid + 256*i; int nl = idx>>5, kl = idx&31;
    wt[blk*2048*768 + (n0+nl)*768 + k0+kl] = f2u(tile[kl][nl]);
  }
}

// ---------------- transpose [wq|wk|wv] (512k x 768n), fold ns[k] -> wqkvt bf16 [768][512] ----------------
__global__ void __launch_bounds__(256) k_tr_qkvw(const float* __restrict__ wq,
    const float* __restrict__ wk, const float* __restrict__ wv,
    const float* __restrict__ ns, ushort* __restrict__ wqkvt)
{
  __shared__ float tile[32][33];
  int blk = blockIdx.z;
  int n0 = blockIdx.x*32, k0 = blockIdx.y*32;
  int tid = threadIdx.x;
  #pragma unroll
  for(int i=0;i<4;i++){
    int idx = tid + 256*i; int kl = idx>>5, nl = idx&31;
    int k = k0+kl, n = n0+nl;
    float v;
    if(n < 512)      v = wq[blk*512*512 + k*512 + n];
    else if(n < 640) v = wk[blk*512*128 + k*128 + (n-512)];
    else             v = wv[blk*512*128 + k*128 + (n-640)];
    tile[kl][nl] = v * ns[blk*512 + k];
  }
  __syncthreads();
  #pragma unroll
  for(int i=0;i<4;i++){
    int idx = tid + 256*i; int nl = idx>>5, kl = idx&31;
    wqkvt[blk*768*512 + (n0+nl)*512 + k0+kl] = f2u(tile[kl][nl]);
  }
}

// ---------------- persistent LSTM scan: all 63 steps in one launch (r3-verified structure) ----------------
// 256 blocks x 256 thr, 1 block/CU (132 KB LDS). Block = (row group g: 64 rows) x (jj tile y: 32 jj x 4 gates).
// Cross-block dep row-local: 16-block group barrier per step via BYTE FLAGS in one 16B line
// (monotonic tag = tagbase+t+1; poll = one sc1 dwordx4 load + 16 byte >= compares; no RMW).
// h stores coalesced: epilogue -> LDS staging tile -> one 16B sc1 store/thread.
// wi B-frags in regs; wh (k 256..767) fully LDS-resident, XOR-swizzled. c-state in regs.
__global__ void __launch_bounds__(256,1) k_lstm_scan(
    const ushort* __restrict__ x, ushort* __restrict__ hs,
    const ushort* __restrict__ wt, const float* __restrict__ bias,
    uchar* __restrict__ flags, int tagbase)
{
  __shared__ __align__(16) short Bwh[128*512];     // 128 KB: c row (gate*32+jjl) x k 256..767, swizzled
  __shared__ __align__(16) ushort hstage[64*32];   // 4 KB h staging
  int fb = blockIdx.x;
  // XCD-grouping heuristic: members of a barrier group share blockIdx%8 -> same XCD
  int g = (fb & 7) | ((fb >> 4) & 8);
  int y = (fb >> 3) & 15;
  int n0 = g*64, jj0 = y*32;
  int tid = threadIdx.x;
  int wv = tid>>6, lane = tid&63, quad = lane>>4, l16 = lane&15;
  int wrow = wv>>1, wcol = wv&1;

  // fill Bwh: 128 c-rows x 64 short8 (k 256..767), 16B-block XOR swizzle by (c&7)
  for(int i=tid; i<8192; i+=256){
    int c = i>>6, kb = i&63;
    short8 v = *(const short8*)(wt + ((c>>5)*512 + jj0 + (c&31))*768 + 256 + kb*8);
    *(short8*)((char*)Bwh + c*1024 + ((kb*16) ^ ((c&7)<<4))) = v;
  }
  // wi B-fragments -> regs (4 gates x 8 k-chunks)
  int jj = jj0 + wcol*16 + l16;
  short8 bwi[4][8];
  #pragma unroll
  for(int gg=0; gg<4; gg++){
    const ushort* wp = wt + (gg*512 + jj)*768 + quad*8;
    #pragma unroll
    for(int ck=0; ck<8; ck++) bwi[gg][ck] = *(const short8*)(wp + ck*32);
  }
  float bI=bias[jj], bF=bias[512+jj], bG=bias[1024+jj], bO=bias[1536+jj];
  float cs[2][4];
  #pragma unroll
  for(int a=0;a<2;a++){
    #pragma unroll
    for(int r=0;r<4;r++) cs[a][r]=0.f;
  }
  const ushort* xb0 = x  + (n0 + wrow*32 + l16)*(NP*256) + quad*8;
  const ushort* hb0 = hs + (n0 + wrow*32 + l16)*(NP*512) + quad*8;
  int xorb = (l16&7)<<4;
  uchar* myflag = flags + g*16 + y;
  const uchar* gflags = flags + g*16;
  __syncthreads();

  for(int t=0; t<NP; ++t){
    f32x4 acc[4][2];
    #pragma unroll
    for(int gg=0; gg<4; gg++){ acc[gg][0]=(f32x4){0.f,0.f,0.f,0.f}; acc[gg][1]=(f32x4){0.f,0.f,0.f,0.f}; }

    // ---- x_t @ wi (k 0..255) — no recurrent dep, runs before the group wait ----
    #pragma unroll
    for(int ck=0; ck<8; ck++){
      short8 a0 = *(const short8*)(xb0 + t*256 + ck*32);
      short8 a1 = *(const short8*)(xb0 + 16*(NP*256) + t*256 + ck*32);
      #pragma unroll
      for(int gg=0; gg<4; gg++){
        acc[gg][0] = __builtin_amdgcn_mfma_f32_16x16x32_bf16(a0, bwi[gg][ck], acc[gg][0], 0,0,0);
        acc[gg][1] = __builtin_amdgcn_mfma_f32_16x16x32_bf16(a1, bwi[gg][ck], acc[gg][1], 0,0,0);
      }
    }

    if(t > 0){
      // ---- group barrier: all 16 flag bytes >= tagbase+t (monotonic; '>=' tolerates fast blocks) ----
      if(tid==0){
        uint tag = (uint)(tagbase + t);
        while(1){
          i32x4 f;
          asm volatile("global_load_dwordx4 %0, %1, off sc0 sc1\n\ts_waitcnt vmcnt(0)"
                       : "=&v"(f) : "v"(gflags) : "memory");
          uint ok = 1u;
          #pragma unroll
          for(int q=0;q<4;q++){
            uint w = (uint)f[q];
            if(( w      &0xffu) < tag) ok=0;
            if(((w>>8 ) &0xffu) < tag) ok=0;
            if(((w>>16) &0xffu) < tag) ok=0;
            if( (w>>24)         < tag) ok=0;
          }
          if(ok) break;
          __builtin_amdgcn_s_sleep(1);
        }
      }
      __syncthreads();

      const ushort* hb = hb0 + (t-1)*512;
      // ---- h @ wh, k 256..767 entirely from LDS ----
      #pragma unroll
      for(int ck=0; ck<16; ck++){
        short8 a0 = *(const short8*)(hb + ck*32);
        short8 a1 = *(const short8*)(hb + 16*(NP*512) + ck*32);
        #pragma unroll
        for(int gg=0; gg<4; gg++){
          int c = gg*32 + wcol*16 + l16;
          short8 bh = *(short8*)((char*)Bwh + c*1024 + ((ck*64 + quad*16) ^ xorb));
          acc[gg][0] = __builtin_amdgcn_mfma_f32_16x16x32_bf16(a0, bh, acc[gg][0], 0,0,0);
          acc[gg][1] = __builtin_amdgcn_mfma_f32_16x16x32_bf16(a1, bh, acc[gg][1], 0,0,0);
        }
      }
    }

    // ---- gates + c-state (regs) + h -> LDS staging (swizzled) ----
    #pragma unroll
    for(int a=0;a<2;a++){
      #pragma unroll
      for(int r=0;r<4;r++){
        int rowl = wrow*32 + a*16 + quad*4 + r;
        float zi=acc[0][a][r]+bI, zf=acc[1][a][r]+bF, zg=acc[2][a][r]+bG, zo=acc[3][a][r]+bO;
        float c = sigf(zf)*cs[a][r] + sigf(zi)*tanhf(zg);
        cs[a][r] = c;
        float hv = sigf(zo)*tanhf(c);
        int coll = wcol*16 + l16;
        int off = rowl*64 + ((coll*2) ^ (((rowl>>2)&3)<<4));
        *(ushort*)((char*)hstage + off) = f2u(hv);
      }
    }
    __syncthreads();
    // ---- coalesced device-visible h store: 256 threads x 16B ----
    {
      int rowl = tid>>2, c0b = (tid&3)*16;
      int off = rowl*64 + (c0b ^ (((rowl>>2)&3)<<4));
      i32x4 vv = *(const i32x4*)((const char*)hstage + off);
      ushort* gp = hs + ((size_t)(n0+rowl)*NP + t)*512 + jj0 + (tid&3)*8;
      asm volatile("global_store_dwordx4 %0, %1, off sc0 sc1" :: "v"(gp), "v"(vv) : "memory");
    }
    __syncthreads();   // drains vmcnt(0) per wave -> all h stores at coherence point
    if(tid==0 && t < NP-1){
      uint v = (uint)(tagbase + t + 1);
      asm volatile("global_store_byte %0, %1, off sc0 sc1" :: "v"(myflag), "v"(v) : "memory");
    }
  }
}

// ---------------- qkv GEMM via MFMA: 64512 x 768, K=512; 128x128 tile; rms fused ----------------
// grid (504, 6): block 128 rows x 128 cols, 4 waves in 2x2 (each 64x64, acc[4][4]).
__global__ void __launch_bounds__(256) k_qkv_m(
    const ushort* __restrict__ hs, const ushort* __restrict__ wqkvt,
    ushort* __restrict__ qkv)
{
  __shared__ short As[128*40];
  __shared__ short Bs[128*40];
  __shared__ float rvs[128];
  int tid = threadIdx.x;
  int r0 = blockIdx.x*128, c0 = blockIdx.y*128;
  int wv = tid>>6, lane = tid&63, quad = lane>>4, l16 = lane&15;
  int wrow = wv>>1, wcol = wv&1;
  int arow0 = tid>>2, akp = tid&3;
  const ushort* aptr[2];
  #pragma unroll
  for(int i=0;i<2;i++){
    int r = r0 + arow0 + i*64;
    int bq = r/8064; int rr = r - bq*8064;
    int m = rr/1008; int rem = rr - m*1008;
    int p = rem>>4; int d = rem&15;
    int n = (bq*16+d)*8+m;
    aptr[i] = hs + (n*NP+p)*512 + akp*8;
  }
  f32x4 acc[4][4];
  #pragma unroll
  for(int b=0;b<4;b++){
    #pragma unroll
    for(int a=0;a<4;a++) acc[b][a] = (f32x4){0.f,0.f,0.f,0.f};
  }
  float ssq0 = 0.f, ssq1 = 0.f;   // fused rms partials for rows arow0, arow0+64
  for(int k0=0;k0<512;k0+=32){
    {
      short8 av = *(const short8*)(aptr[0] + k0);
      *(short8*)&As[arow0*40 + akp*8] = av;
      #pragma unroll
      for(int e=0;e<8;e++){ float vv = u2f((ushort)av[e]); ssq0 = fmaf(vv, vv, ssq0); }
    }
    {
      short8 av = *(const short8*)(aptr[1] + k0);
      *(short8*)&As[(arow0+64)*40 + akp*8] = av;
      #pragma unroll
      for(int e=0;e<8;e++){ float vv = u2f((ushort)av[e]); ssq1 = fmaf(vv, vv, ssq1); }
    }
    #pragma unroll
    for(int i=0;i<2;i++){
      int pc = tid + 256*i; int rl=pc>>2, kp=pc&3;
      *(short8*)&Bs[rl*40+kp*8] = *(const short8*)(wqkvt + (c0+rl)*512 + k0 + kp*8);
    }
    __syncthreads();
    short8 af[4], bfr[4];
    #pragma unroll
    for(int a=0;a<4;a++) af[a] = *(short8*)&As[(wrow*64 + a*16 + l16)*40 + quad*8];
    #pragma unroll
    for(int b=0;b<4;b++) bfr[b] = *(short8*)&Bs[(wcol*64 + b*16 + l16)*40 + quad*8];
    #pragma unroll
    for(int b=0;b<4;b++){
      #pragma unroll
      for(int a=0;a<4;a++)
        acc[b][a] = __builtin_amdgcn_mfma_f32_16x16x32_bf16(af[a], bfr[b], acc[b][a], 0,0,0);
    }
    __syncthreads();
  }
  // reduce ssq across the 4 threads (akp 0..3) sharing each row
  ssq0 += __shfl_xor(ssq0, 1); ssq0 += __shfl_xor(ssq0, 2);
  ssq1 += __shfl_xor(ssq1, 1); ssq1 += __shfl_xor(ssq1, 2);
  if(akp==0){
    rvs[arow0]    = rsqrtf(ssq0*(1.f/512.f)+1e-6f);
    rvs[arow0+64] = rsqrtf(ssq1*(1.f/512.f)+1e-6f);
  }
  __syncthreads();
  #pragma unroll
  for(int a=0;a<4;a++){
    #pragma unroll
    for(int rg=0;rg<4;rg++){
      int rowl = wrow*64 + a*16 + quad*4 + rg;
      int rw = r0 + rowl;
      float rv = rvs[rowl];
      #pragma unroll
      for(int b=0;b<4;b++){
        int c = c0 + wcol*64 + b*16 + l16;
        qkv[rw*768 + c] = f2u(acc[b][a][rg] * rv);
      }
    }
  }
}

// ---------------- attention (bf16 qkv buffer): per (row16-group, head) ----------------
__global__ void __launch_bounds__(256) k_attn(ushort* __restrict__ qkv)
{
  int r3 = blockIdx.x, h = blockIdx.y;
  int tid = threadIdx.x;
  __shared__ float qs[16][64];
  __shared__ float ks[16][65];
  __shared__ float vs[16][64];
  __shared__ float P[16][17];
  ushort* base = qkv + r3*16*768;
  int xx = tid&63, s4 = tid>>6;
  int kvh = (h>>2)*64;
  #pragma unroll
  for(int a=0;a<4;a++){
    int s = s4 + 4*a;
    qs[s][xx] = u2f(base[s*768 + h*64 + xx]);
    ks[s][xx] = u2f(base[s*768 + 512 + kvh + xx]);
    vs[s][xx] = u2f(base[s*768 + 640 + kvh + xx]);
  }
  __syncthreads();
  int i = tid>>4, j = tid&15;
  float sc = 0.f;
  #pragma unroll
  for(int xq=0;xq<64;xq++) sc = fmaf(qs[i][xq], ks[j][xq], sc);
  P[i][j] = sc*0.125f;
  __syncthreads();
  float row[16];
  #pragma unroll
  for(int jj=0;jj<16;jj++) row[jj] = P[i][jj];
  float mx = row[0];
  #pragma unroll
  for(int jj=1;jj<16;jj++) mx = fmaxf(mx, row[jj]);
  float sum = 0.f;
  #pragma unroll
  for(int jj=0;jj<16;jj++) sum += expf(row[jj]-mx);
  float pme = expf(row[j]-mx)/sum;
  __syncthreads();
  P[i][j] = pme;
  __syncthreads();
  #pragma unroll
  for(int a=0;a<4;a++){
    int s = s4 + 4*a;
    float o = 0.f;
    #pragma unroll
    for(int jj=0;jj<16;jj++) o = fmaf(P[s][jj], vs[jj][xx], o);
    base[s*768 + h*64 + xx] = f2u(o);
  }
}

// ---------------- bel GEMM via MFMA: O(64512x512 in qkv) @ wodt^T -> scatter bf16 xbuf ----------------
// grid (504, 2): block 128 x 128, 4 waves in 2x2 (each 64x64, acc[4][4]).
__global__ void __launch_bounds__(256) k_bel_m(
    const ushort* __restrict__ qkv, const ushort* __restrict__ wodt,
    ushort* __restrict__ x)
{
  __shared__ short As[128*40];
  __shared__ short Bs[128*40];
  int tid = threadIdx.x;
  int r0 = blockIdx.x*128, c0 = blockIdx.y*128;
  int wv = tid>>6, lane = tid&63, quad = lane>>4, l16 = lane&15;
  int wrow = wv>>1, wcol = wv&1;
  int arow0 = tid>>2, akp = tid&3;
  const ushort* aptr0 = qkv + (r0+arow0)*768 + akp*8;
  const ushort* aptr1 = qkv + (r0+arow0+64)*768 + akp*8;
  f32x4 acc[4][4];
  #pragma unroll
  for(int b=0;b<4;b++){
    #pragma unroll
    for(int a=0;a<4;a++) acc[b][a] = (f32x4){0.f,0.f,0.f,0.f};
  }
  for(int k0=0;k0<512;k0+=32){
    *(short8*)&As[arow0*40 + akp*8]      = *(const short8*)(aptr0 + k0);
    *(short8*)&As[(arow0+64)*40 + akp*8] = *(const short8*)(aptr1 + k0);
    #pragma unroll
    for(int i=0;i<2;i++){
      int pc = tid + 256*i; int rl=pc>>2, kp=pc&3;
      *(short8*)&Bs[rl*40+kp*8] = *(const short8*)(wodt + (c0+rl)*512 + k0 + kp*8);
    }
    __syncthreads();
    short8 af[4], bfr[4];
    #pragma unroll
    for(int a=0;a<4;a++) af[a] = *(short8*)&As[(wrow*64 + a*16 + l16)*40 + quad*8];
    #pragma unroll
    for(int b=0;b<4;b++) bfr[b] = *(short8*)&Bs[(wcol*64 + b*16 + l16)*40 + quad*8];
    #pragma unroll
    for(int b=0;b<4;b++){
      #pragma unroll
      for(int a=0;a<4;a++)
        acc[b][a] = __builtin_amdgcn_mfma_f32_16x16x32_bf16(af[a], bfr[b], acc[b][a], 0,0,0);
    }
    __syncthreads();
  }
  #pragma unroll
  for(int a=0;a<4;a++){
    #pragma unroll
    for(int rg=0;rg<4;rg++){
      int rw = r0 + wrow*64 + a*16 + quad*4 + rg;
      int bq = rw/8064; int rr = rw - bq*8064;
      int m = rr/1008; int rem = rr - m*1008;
      int p = rem>>4; int d = rem&15;
      int n = (bq*16+d)*8+m;
      ushort* xo = x + (n*NP+p)*256;
      #pragma unroll
      for(int b=0;b<4;b++){
        int c = c0 + wcol*64 + b*16 + l16;
        xo[c] = f2u(acc[b][a][rg]);
      }
    }
  }
}

// ---------------- head ----------------
__global__ void __launch_bounds__(256) k_head(const ushort* __restrict__ x,
    const float* __restrict__ meanv, const float* __restrict__ stdv,
    const float* __restrict__ rs, const float* __restrict__ rb,
    const float* __restrict__ hns, const float* __restrict__ pw,
    const float* __restrict__ qw, float* __restrict__ out)
{
  int n = blockIdx.x, tid = threadIdx.x;
  __shared__ float nb[256];
  __shared__ float red[256];
  float v = u2f(x[(n*NP + 62)*256 + tid]);
  red[tid] = v*v; __syncthreads();
  for(int s=128;s>0;s>>=1){
    if(tid<s) red[tid]+=red[tid+s];
    __syncthreads();
  }
  float rinv = rsqrtf(red[0]*(1.f/256.f)+1e-6f);
  nb[tid] = v*rinv*hns[tid];
  __syncthreads();
  int m = n&7;
  float mu=meanv[n], sd=stdv[n], sc=rs[m], bi=rb[m];
  for(int col=tid; col<384; col+=256){
    float acc=0.f;
    int slot, hh;
    if(col < 96){
      for(int k=0;k<256;k++) acc = fmaf(nb[k], pw[k*96+col], acc);
      slot = 0; hh = col;
    } else {
      int cq = col-96;
      for(int k=0;k<256;k++) acc = fmaf(nb[k], qw[k*288+cq], acc);
      int qi = cq - (cq/3)*3;
      slot = 1 + qi; hh = cq/3;
    }
    float y = (acc - bi)/sc*sd + mu;
    out[(slot*1024 + n)*96 + hh] = y;
  }
}

extern "C" void kernel_launch(void* const* d_in, const int* in_sizes, int n_in,
                              void* d_out, int out_size, void* d_ws, size_t ws_size,
                              hipStream_t stream)
{
  const float* series    = (const float*)d_in[0];
  const float* rs        = (const float*)d_in[1];
  const float* rb        = (const float*)d_in[2];
  const float* up_w      = (const float*)d_in[3];
  const float* lstm_wi   = (const float*)d_in[4];
  const float* lstm_wh   = (const float*)d_in[5];
  const float* lstm_b    = (const float*)d_in[6];
  const float* norm_scale= (const float*)d_in[7];
  const float* wq        = (const float*)d_in[8];
  const float* wk        = (const float*)d_in[9];
  const float* wv        = (const float*)d_in[10];
  const float* wo        = (const float*)d_in[11];
  const float* down_w    = (const float*)d_in[12];
  const float* head_ns   = (const float*)d_in[13];
  const float* point_w   = (const float*)d_in[14];
  const float* quant_w   = (const float*)d_in[15];
  float* out = (float*)d_out;

  float* ws = (float*)d_ws;
  float*  meanv = ws;                       // 1024
  float*  stdv  = meanv + 1024;             // 1024
  float*  rmsi  = stdv  + 1024;             // 64512 (unused now; kept for layout stability)
  float*  cst   = rmsi  + 64512;            // 524288 (c-state in regs; start reused for flag bytes)
  float*  wodf  = cst   + 524288;           // 524288
  ushort* xbuf  = (ushort*)(wodf + 524288);         // 16515072 bf16
  ushort* hsb   = xbuf  + 16515072;                 // 33030144 bf16
  ushort* qkvb  = hsb   + 33030144;                 // 49545216 bf16
  ushort* wt    = qkvb  + 49545216;                 // 6291456 bf16
  ushort* wqkvt = wt    + 6291456;                  // 1572864 bf16
  ushort* wodt  = wqkvt + 1572864;                  // 524288 bf16
  int*    bar   = (int*)cst;                        // 256 flag bytes (16 groups x 16 blocks)

  k_revin<<<1024,256,0,stream>>>(series, meanv, stdv, bar);
  k_patch<<<1024,256,0,stream>>>(series, rs, rb, up_w, meanv, stdv, xbuf);
  k_wod<<<dim3(512,4),256,0,stream>>>(wo, down_w, wodf);
  k_tr_wodt<<<dim3(8,16,4),256,0,stream>>>(wodf, wodt);
  k_tr_lstmw<<<dim3(64,24,4),256,0,stream>>>(lstm_wi, lstm_wh, wt);
  k_tr_qkvw<<<dim3(24,16,4),256,0,stream>>>(wq, wk, wv, norm_scale, wqkvt);

  for(int blk=0; blk<4; blk++){
    const ushort* wt_b = wt + blk*2048*768;
    const float*  bb   = lstm_b + blk*2048;
    k_lstm_scan<<<256,256,0,stream>>>(xbuf, hsb, wt_b, bb, (uchar*)bar, blk*NP);
    k_qkv_m<<<dim3(504,6),256,0,stream>>>(hsb, wqkvt + blk*768*512, qkvb);
    k_attn<<<dim3(4032,8),256,0,stream>>>(qkvb);
    k_bel_m<<<dim3(504,2),256,0,stream>>>(qkvb, wodt + blk*256*512, xbuf);
  }
  k_head<<<1024,256,0,stream>>>(xbuf, meanv, stdv, rs, rb, head_ns, point_w, quant_w, out);
}

// Round 9
// 3604.858 us; speedup vs baseline: 1.6418x; 1.0073x over previous
//
#include <hip/hip_runtime.h>
#include <hip/hip_bf16.h>

#define NP 63   // number of patches

typedef __attribute__((ext_vector_type(8))) short short8;
typedef __attribute__((ext_vector_type(4))) float f32x4;
typedef __attribute__((ext_vector_type(4))) int i32x4;
typedef unsigned char uchar;

__device__ __forceinline__ float sigf(float x){ return 1.0f/(1.0f+expf(-x)); }
__device__ __forceinline__ float u2f(ushort u){ __hip_bfloat16 h; *(ushort*)&h = u; return __bfloat162float(h); }
__device__ __forceinline__ ushort f2u(float f){ __hip_bfloat16 h = __float2bfloat16(f); return *(ushort*)&h; }

// ---------------- RevIN stats (+ zero persistent-scan flag/detect bytes) ----------------
__global__ void __launch_bounds__(256) k_revin(const float* __restrict__ series,
    float* __restrict__ meanv, float* __restrict__ stdv, int* __restrict__ bar)
{
  int n = blockIdx.x, tid = threadIdx.x;
  if(n==0){ for(int i=tid;i<320;i+=256) bar[i]=0; }  // 256B flags + 4x256B XCD-detect
  __shared__ float s1[256], s2[256];
  const float* p = series + n*512;
  float a = 0.f, b = 0.f;
  for(int t=tid;t<512;t+=256){ float v=p[t]; a+=v; b+=v*v; }
  s1[tid]=a; s2[tid]=b; __syncthreads();
  for(int s=128;s>0;s>>=1){
    if(tid<s){ s1[tid]+=s1[tid+s]; s2[tid]+=s2[tid+s]; }
    __syncthreads();
  }
  if(tid==0){
    float mu = s1[0]*(1.f/512.f);
    float var = fmaxf(s2[0]*(1.f/512.f) - mu*mu, 0.f);
    meanv[n]=mu; stdv[n]=sqrtf(var+1e-5f);
  }
}

// ---------------- patch embed -> bf16 xbuf ----------------
__global__ void __launch_bounds__(256) k_patch(const float* __restrict__ series,
    const float* __restrict__ rs, const float* __restrict__ rb,
    const float* __restrict__ up_w, const float* __restrict__ meanv,
    const float* __restrict__ stdv, ushort* __restrict__ x)
{
  int n = blockIdx.x, tid = threadIdx.x;
  int m = n & 7;
  __shared__ float sn[512];
  float mu = meanv[n], sd = stdv[n];
  float A = rs[m]/sd, C = rb[m] - mu*A;
  const float* p = series + n*512;
  for(int t=tid;t<512;t+=256) sn[t] = p[t]*A + C;
  __syncthreads();
  float w[16];
  #pragma unroll
  for(int i=0;i<16;i++) w[i] = up_w[i*256+tid];
  ushort* xo = x + n*(NP*256);
  for(int pi=0;pi<NP;pi++){
    float acc=0.f;
    #pragma unroll
    for(int i=0;i<16;i++) acc = fmaf(sn[pi*8+i], w[i], acc);
    xo[pi*256+tid] = f2u(acc);
  }
}

// ---------------- W_od = wo @ down_w (f32) ----------------
__global__ void __launch_bounds__(256) k_wod(const float* __restrict__ wo,
    const float* __restrict__ dw, float* __restrict__ wod)
{
  int i = blockIdx.x, blk = blockIdx.y, tid = threadIdx.x;
  __shared__ float row[512];
  const float* wr = wo + (blk*512 + i)*512;
  for(int k=tid;k<512;k+=256) row[k]=wr[k];
  __syncthreads();
  const float* d = dw + blk*512*256;
  float acc=0.f;
  for(int k=0;k<512;k++) acc = fmaf(row[k], d[k*256+tid], acc);
  wod[(blk*512+i)*256+tid]=acc;
}

// ---------------- transpose wod (512k x 256n) -> wodt bf16 [256][512] ----------------
__global__ void __launch_bounds__(256) k_tr_wodt(const float* __restrict__ wod, ushort* __restrict__ wodt)
{
  __shared__ float tile[32][33];
  int blk = blockIdx.z;
  int n0 = blockIdx.x*32, k0 = blockIdx.y*32;
  int tid = threadIdx.x;
  #pragma unroll
  for(int i=0;i<4;i++){
    int idx = tid + 256*i; int kl = idx>>5, nl = idx&31;
    tile[kl][nl] = wod[blk*512*256 + (k0+kl)*256 + n0+nl];
  }
  __syncthreads();
  #pragma unroll
  for(int i=0;i<4;i++){
    int idx = tid + 256*i; int nl = idx>>5, kl = idx&31;
    wodt[blk*256*512 + (n0+nl)*512 + k0+kl] = f2u(tile[kl][nl]);
  }
}

// ---------------- transpose [wi;wh] (768k x 2048n) -> wt bf16 [2048][768] ----------------
__global__ void __launch_bounds__(256) k_tr_lstmw(const float* __restrict__ wi,
    const float* __restrict__ wh, ushort* __restrict__ wt)
{
  __shared__ float tile[32][33];
  int blk = blockIdx.z;
  int n0 = blockIdx.x*32, k0 = blockIdx.y*32;
  int tid = threadIdx.x;
  #pragma unroll
  for(int i=0;i<4;i++){
    int idx = tid + 256*i; int kl = idx>>5, nl = idx&31;
    int k = k0+kl, n = n0+nl;
    float v = (k<256) ? wi[blk*256*2048 + k*2048 + n]
                      : wh[blk*512*2048 + (k-256)*2048 + n];
    tile[kl][nl] = v;
  }
  __syncthreads();
  #pragma unroll
  for(int i=0;i<4;i++){
    int idx = tid + 256*i; int nl = idx>>5, kl = idx&31;
    wt[blk*2048*768 + (n0+nl)*768 + k0+kl] = f2u(tile[kl][nl]);
  }
}

// ---------------- transpose [wq|wk|wv] (512k x 768n), fold ns[k] -> wqkvt bf16 [768][512] ----------------
__global__ void __launch_bounds__(256) k_tr_qkvw(const float* __restrict__ wq,
    const float* __restrict__ wk, const float* __restrict__ wv,
    const float* __restrict__ ns, ushort* __restrict__ wqkvt)
{
  __shared__ float tile[32][33];
  int blk = blockIdx.z;
  int n0 = blockIdx.x*32, k0 = blockIdx.y*32;
  int tid = threadIdx.x;
  #pragma unroll
  for(int i=0;i<4;i++){
    int idx = tid + 256*i; int kl = idx>>5, nl = idx&31;
    int k = k0+kl, n = n0+nl;
    float v;
    if(n < 512)      v = wq[blk*512*512 + k*512 + n];
    else if(n < 640) v = wk[blk*512*128 + k*128 + (n-512)];
    else             v = wv[blk*512*128 + k*128 + (n-640)];
    tile[kl][nl] = v * ns[blk*512 + k];
  }
  __syncthreads();
  #pragma unroll
  for(int i=0;i<4;i++){
    int idx = tid + 256*i; int nl = idx>>5, kl = idx&31;
    wqkvt[blk*768*512 + (n0+nl)*512 + k0+kl] = f2u(tile[kl][nl]);
  }
}

// ---------------- persistent LSTM scan (r3 structure + runtime-verified same-XCD fast sync) ----------------
// 256 blocks x 256 thr, 1 block/CU. Block = (row group g: 64 rows) x (jj tile y: 32 jj x 4 gates).
// Group members share fb&7 -> same XCD under round-robin dispatch. At launch start each block
// publishes its HW_REG_XCC_ID (sc1); tid0 verifies all 16 group members match -> FAST.
// FAST: h stores/flags are PLAIN (land in the shared per-XCD L2, ~0.2us), polls are sc0-only
// (bypass L1, hit local L2). Cross-kernel visibility comes from the dispatch-boundary L2
// writeback/invalidate (proof: k_patch's plain stores are read correctly by this kernel today).
// SLOW (mismatch): byte-identical r3 path (sc1 write-through everywhere). Numerics identical.
__global__ void __launch_bounds__(256,1) k_lstm_scan(
    const ushort* __restrict__ x, ushort* __restrict__ hs,
    const ushort* __restrict__ wt, const float* __restrict__ bias,
    uchar* __restrict__ flags, int tagbase, uchar* __restrict__ detect)
{
  __shared__ __align__(16) short Bwh[128*512];     // 128 KB: c row (gate*32+jjl) x k 256..767, swizzled
  __shared__ __align__(16) ushort hstage[64*32];   // 4 KB h staging
  __shared__ int fastflag;
  int fb = blockIdx.x;
  // XCD-grouping: members of a barrier group share blockIdx%8 -> same XCD (verified below)
  int g = (fb & 7) | ((fb >> 4) & 8);
  int y = (fb >> 3) & 15;
  int n0 = g*64, jj0 = y*32;
  int tid = threadIdx.x;
  int wv = tid>>6, lane = tid&63, quad = lane>>4, l16 = lane&15;
  int wrow = wv>>1, wcol = wv&1;

  // fill Bwh: 128 c-rows x 64 short8 (k 256..767), 16B-block XOR swizzle by (c&7)
  for(int i=tid; i<8192; i+=256){
    int c = i>>6, kb = i&63;
    short8 v = *(const short8*)(wt + ((c>>5)*512 + jj0 + (c&31))*768 + 256 + kb*8);
    *(short8*)((char*)Bwh + c*1024 + ((kb*16) ^ ((c&7)<<4))) = v;
  }
  // wi B-fragments -> regs (4 gates x 8 k-chunks)
  int jj = jj0 + wcol*16 + l16;
  short8 bwi[4][8];
  #pragma unroll
  for(int gg=0; gg<4; gg++){
    const ushort* wp = wt + (gg*512 + jj)*768 + quad*8;
    #pragma unroll
    for(int ck=0; ck<8; ck++) bwi[gg][ck] = *(const short8*)(wp + ck*32);
  }
  float bI=bias[jj], bF=bias[512+jj], bG=bias[1024+jj], bO=bias[1536+jj];
  float cs[2][4];
  #pragma unroll
  for(int a=0;a<2;a++){
    #pragma unroll
    for(int r=0;r<4;r++) cs[a][r]=0.f;
  }
  const ushort* xb0 = x  + (n0 + wrow*32 + l16)*(NP*256) + quad*8;
  const ushort* hb0 = hs + (n0 + wrow*32 + l16)*(NP*512) + quad*8;
  int xorb = (l16&7)<<4;
  uchar* myflag = flags + g*16 + y;
  const uchar* gflags = flags + g*16;

  // ---- same-XCD detection (device-visible; one-time) ----
  if(tid==0){
    uint xcc = __builtin_amdgcn_s_getreg(63508) & 0xfu;   // HW_REG_XCC_ID(20), offset 0, size 32
    uint myid = xcc + 1u;
    uchar* dp = detect + g*16 + y;
    asm volatile("global_store_byte %0, %1, off sc0 sc1" :: "v"(dp), "v"(myid) : "memory");
    const uchar* dq = detect + g*16;
    while(1){
      i32x4 f;
      asm volatile("global_load_dwordx4 %0, %1, off sc0 sc1\n\ts_waitcnt vmcnt(0)"
                   : "=&v"(f) : "v"(dq) : "memory");
      uint allnz=1u, alleq=1u;
      #pragma unroll
      for(int q=0;q<4;q++){
        uint w=(uint)f[q];
        #pragma unroll
        for(int b=0;b<4;b++){
          uint bv = (w>>(8*b))&0xffu;
          if(bv==0u) allnz=0u;
          else if(bv!=myid) alleq=0u;
        }
      }
      if(allnz){ fastflag = (int)alleq; break; }
      __builtin_amdgcn_s_sleep(2);
    }
  }
  __syncthreads();   // Bwh ready + fastflag ready
  const int FAST = fastflag;

  for(int t=0; t<NP; ++t){
    f32x4 acc[4][2];
    #pragma unroll
    for(int gg=0; gg<4; gg++){ acc[gg][0]=(f32x4){0.f,0.f,0.f,0.f}; acc[gg][1]=(f32x4){0.f,0.f,0.f,0.f}; }

    // ---- x_t @ wi (k 0..255) — no recurrent dep, runs before the group wait ----
    #pragma unroll
    for(int ck=0; ck<8; ck++){
      short8 a0 = *(const short8*)(xb0 + t*256 + ck*32);
      short8 a1 = *(const short8*)(xb0 + 16*(NP*256) + t*256 + ck*32);
      #pragma unroll
      for(int gg=0; gg<4; gg++){
        acc[gg][0] = __builtin_amdgcn_mfma_f32_16x16x32_bf16(a0, bwi[gg][ck], acc[gg][0], 0,0,0);
        acc[gg][1] = __builtin_amdgcn_mfma_f32_16x16x32_bf16(a1, bwi[gg][ck], acc[gg][1], 0,0,0);
      }
    }

    if(t > 0){
      // ---- group barrier: all 16 flag bytes >= tagbase+t (monotonic) ----
      if(tid==0){
        uint tag = (uint)(tagbase + t);
        while(1){
          i32x4 f;
          if(FAST)
            asm volatile("global_load_dwordx4 %0, %1, off sc0\n\ts_waitcnt vmcnt(0)"
                         : "=&v"(f) : "v"(gflags) : "memory");
          else
            asm volatile("global_load_dwordx4 %0, %1, off sc0 sc1\n\ts_waitcnt vmcnt(0)"
                         : "=&v"(f) : "v"(gflags) : "memory");
          uint ok = 1u;
          #pragma unroll
          for(int q=0;q<4;q++){
            uint w = (uint)f[q];
            if(( w      &0xffu) < tag) ok=0;
            if(((w>>8 ) &0xffu) < tag) ok=0;
            if(((w>>16) &0xffu) < tag) ok=0;
            if( (w>>24)         < tag) ok=0;
          }
          if(ok) break;
          __builtin_amdgcn_s_sleep(1);
        }
      }
      __syncthreads();

      const ushort* hb = hb0 + (t-1)*512;
      // ---- h @ wh, k 256..767 entirely from LDS ----
      #pragma unroll
      for(int ck=0; ck<16; ck++){
        short8 a0 = *(const short8*)(hb + ck*32);
        short8 a1 = *(const short8*)(hb + 16*(NP*512) + ck*32);
        #pragma unroll
        for(int gg=0; gg<4; gg++){
          int c = gg*32 + wcol*16 + l16;
          short8 bh = *(short8*)((char*)Bwh + c*1024 + ((ck*64 + quad*16) ^ xorb));
          acc[gg][0] = __builtin_amdgcn_mfma_f32_16x16x32_bf16(a0, bh, acc[gg][0], 0,0,0);
          acc[gg][1] = __builtin_amdgcn_mfma_f32_16x16x32_bf16(a1, bh, acc[gg][1], 0,0,0);
        }
      }
    }

    // ---- gates + c-state (regs) + h -> LDS staging (swizzled) ----
    #pragma unroll
    for(int a=0;a<2;a++){
      #pragma unroll
      for(int r=0;r<4;r++){
        int rowl = wrow*32 + a*16 + quad*4 + r;
        float zi=acc[0][a][r]+bI, zf=acc[1][a][r]+bF, zg=acc[2][a][r]+bG, zo=acc[3][a][r]+bO;
        float c = sigf(zf)*cs[a][r] + sigf(zi)*tanhf(zg);
        cs[a][r] = c;
        float hv = sigf(zo)*tanhf(c);
        int coll = wcol*16 + l16;
        int off = rowl*64 + ((coll*2) ^ (((rowl>>2)&3)<<4));
        *(ushort*)((char*)hstage + off) = f2u(hv);
      }
    }
    __syncthreads();
    // ---- coalesced h store: 256 threads x 16B. FAST: plain (local L2); SLOW: sc1 (IC) ----
    {
      int rowl = tid>>2, c0b = (tid&3)*16;
      int off = rowl*64 + (c0b ^ (((rowl>>2)&3)<<4));
      i32x4 vv = *(const i32x4*)((const char*)hstage + off);
      ushort* gp = hs + ((size_t)(n0+rowl)*NP + t)*512 + jj0 + (tid&3)*8;
      if(FAST)
        asm volatile("global_store_dwordx4 %0, %1, off" :: "v"(gp), "v"(vv) : "memory");
      else
        asm volatile("global_store_dwordx4 %0, %1, off sc0 sc1" :: "v"(gp), "v"(vv) : "memory");
    }
    __syncthreads();   // drains vmcnt(0) per wave -> h visible at the path's coherence point
    if(tid==0 && t < NP-1){
      uint v = (uint)(tagbase + t + 1);
      if(FAST)
        asm volatile("global_store_byte %0, %1, off" :: "v"(myflag), "v"(v) : "memory");
      else
        asm volatile("global_store_byte %0, %1, off sc0 sc1" :: "v"(myflag), "v"(v) : "memory");
    }
  }
}

// ---------------- qkv GEMM via MFMA: 64512 x 768, K=512; 128x128 tile; rms fused ----------------
__global__ void __launch_bounds__(256) k_qkv_m(
    const ushort* __restrict__ hs, const ushort* __restrict__ wqkvt,
    ushort* __restrict__ qkv)
{
  __shared__ short As[128*40];
  __shared__ short Bs[128*40];
  __shared__ float rvs[128];
  int tid = threadIdx.x;
  int r0 = blockIdx.x*128, c0 = blockIdx.y*128;
  int wv = tid>>6, lane = tid&63, quad = lane>>4, l16 = lane&15;
  int wrow = wv>>1, wcol = wv&1;
  int arow0 = tid>>2, akp = tid&3;
  const ushort* aptr[2];
  #pragma unroll
  for(int i=0;i<2;i++){
    int r = r0 + arow0 + i*64;
    int bq = r/8064; int rr = r - bq*8064;
    int m = rr/1008; int rem = rr - m*1008;
    int p = rem>>4; int d = rem&15;
    int n = (bq*16+d)*8+m;
    aptr[i] = hs + (n*NP+p)*512 + akp*8;
  }
  f32x4 acc[4][4];
  #pragma unroll
  for(int b=0;b<4;b++){
    #pragma unroll
    for(int a=0;a<4;a++) acc[b][a] = (f32x4){0.f,0.f,0.f,0.f};
  }
  float ssq0 = 0.f, ssq1 = 0.f;
  for(int k0=0;k0<512;k0+=32){
    {
      short8 av = *(const short8*)(aptr[0] + k0);
      *(short8*)&As[arow0*40 + akp*8] = av;
      #pragma unroll
      for(int e=0;e<8;e++){ float vv = u2f((ushort)av[e]); ssq0 = fmaf(vv, vv, ssq0); }
    }
    {
      short8 av = *(const short8*)(aptr[1] + k0);
      *(short8*)&As[(arow0+64)*40 + akp*8] = av;
      #pragma unroll
      for(int e=0;e<8;e++){ float vv = u2f((ushort)av[e]); ssq1 = fmaf(vv, vv, ssq1); }
    }
    #pragma unroll
    for(int i=0;i<2;i++){
      int pc = tid + 256*i; int rl=pc>>2, kp=pc&3;
      *(short8*)&Bs[rl*40+kp*8] = *(const short8*)(wqkvt + (c0+rl)*512 + k0 + kp*8);
    }
    __syncthreads();
    short8 af[4], bfr[4];
    #pragma unroll
    for(int a=0;a<4;a++) af[a] = *(short8*)&As[(wrow*64 + a*16 + l16)*40 + quad*8];
    #pragma unroll
    for(int b=0;b<4;b++) bfr[b] = *(short8*)&Bs[(wcol*64 + b*16 + l16)*40 + quad*8];
    #pragma unroll
    for(int b=0;b<4;b++){
      #pragma unroll
      for(int a=0;a<4;a++)
        acc[b][a] = __builtin_amdgcn_mfma_f32_16x16x32_bf16(af[a], bfr[b], acc[b][a], 0,0,0);
    }
    __syncthreads();
  }
  ssq0 += __shfl_xor(ssq0, 1); ssq0 += __shfl_xor(ssq0, 2);
  ssq1 += __shfl_xor(ssq1, 1); ssq1 += __shfl_xor(ssq1, 2);
  if(akp==0){
    rvs[arow0]    = rsqrtf(ssq0*(1.f/512.f)+1e-6f);
    rvs[arow0+64] = rsqrtf(ssq1*(1.f/512.f)+1e-6f);
  }
  __syncthreads();
  #pragma unroll
  for(int a=0;a<4;a++){
    #pragma unroll
    for(int rg=0;rg<4;rg++){
      int rowl = wrow*64 + a*16 + quad*4 + rg;
      int rw = r0 + rowl;
      float rv = rvs[rowl];
      #pragma unroll
      for(int b=0;b<4;b++){
        int c = c0 + wcol*64 + b*16 + l16;
        qkv[rw*768 + c] = f2u(acc[b][a][rg] * rv);
      }
    }
  }
}

// ---------------- attention (bf16 qkv buffer): per (row16-group, head) ----------------
__global__ void __launch_bounds__(256) k_attn(ushort* __restrict__ qkv)
{
  int r3 = blockIdx.x, h = blockIdx.y;
  int tid = threadIdx.x;
  __shared__ float qs[16][64];
  __shared__ float ks[16][65];
  __shared__ float vs[16][64];
  __shared__ float P[16][17];
  ushort* base = qkv + r3*16*768;
  int xx = tid&63, s4 = tid>>6;
  int kvh = (h>>2)*64;
  #pragma unroll
  for(int a=0;a<4;a++){
    int s = s4 + 4*a;
    qs[s][xx] = u2f(base[s*768 + h*64 + xx]);
    ks[s][xx] = u2f(base[s*768 + 512 + kvh + xx]);
    vs[s][xx] = u2f(base[s*768 + 640 + kvh + xx]);
  }
  __syncthreads();
  int i = tid>>4, j = tid&15;
  float sc = 0.f;
  #pragma unroll
  for(int xq=0;xq<64;xq++) sc = fmaf(qs[i][xq], ks[j][xq], sc);
  P[i][j] = sc*0.125f;
  __syncthreads();
  float row[16];
  #pragma unroll
  for(int jj=0;jj<16;jj++) row[jj] = P[i][jj];
  float mx = row[0];
  #pragma unroll
  for(int jj=1;jj<16;jj++) mx = fmaxf(mx, row[jj]);
  float sum = 0.f;
  #pragma unroll
  for(int jj=0;jj<16;jj++) sum += expf(row[jj]-mx);
  float pme = expf(row[j]-mx)/sum;
  __syncthreads();
  P[i][j] = pme;
  __syncthreads();
  #pragma unroll
  for(int a=0;a<4;a++){
    int s = s4 + 4*a;
    float o = 0.f;
    #pragma unroll
    for(int jj=0;jj<16;jj++) o = fmaf(P[s][jj], vs[jj][xx], o);
    base[s*768 + h*64 + xx] = f2u(o);
  }
}

// ---------------- bel GEMM via MFMA: O(64512x512 in qkv) @ wodt^T -> scatter bf16 xbuf ----------------
__global__ void __launch_bounds__(256) k_bel_m(
    const ushort* __restrict__ qkv, const ushort* __restrict__ wodt,
    ushort* __restrict__ x)
{
  __shared__ short As[128*40];
  __shared__ short Bs[128*40];
  int tid = threadIdx.x;
  int r0 = blockIdx.x*128, c0 = blockIdx.y*128;
  int wv = tid>>6, lane = tid&63, quad = lane>>4, l16 = lane&15;
  int wrow = wv>>1, wcol = wv&1;
  int arow0 = tid>>2, akp = tid&3;
  const ushort* aptr0 = qkv + (r0+arow0)*768 + akp*8;
  const ushort* aptr1 = qkv + (r0+arow0+64)*768 + akp*8;
  f32x4 acc[4][4];
  #pragma unroll
  for(int b=0;b<4;b++){
    #pragma unroll
    for(int a=0;a<4;a++) acc[b][a] = (f32x4){0.f,0.f,0.f,0.f};
  }
  for(int k0=0;k0<512;k0+=32){
    *(short8*)&As[arow0*40 + akp*8]      = *(const short8*)(aptr0 + k0);
    *(short8*)&As[(arow0+64)*40 + akp*8] = *(const short8*)(aptr1 + k0);
    #pragma unroll
    for(int i=0;i<2;i++){
      int pc = tid + 256*i; int rl=pc>>2, kp=pc&3;
      *(short8*)&Bs[rl*40+kp*8] = *(const short8*)(wodt + (c0+rl)*512 + k0 + kp*8);
    }
    __syncthreads();
    short8 af[4], bfr[4];
    #pragma unroll
    for(int a=0;a<4;a++) af[a] = *(short8*)&As[(wrow*64 + a*16 + l16)*40 + quad*8];
    #pragma unroll
    for(int b=0;b<4;b++) bfr[b] = *(short8*)&Bs[(wcol*64 + b*16 + l16)*40 + quad*8];
    #pragma unroll
    for(int b=0;b<4;b++){
      #pragma unroll
      for(int a=0;a<4;a++)
        acc[b][a] = __builtin_amdgcn_mfma_f32_16x16x32_bf16(af[a], bfr[b], acc[b][a], 0,0,0);
    }
    __syncthreads();
  }
  #pragma unroll
  for(int a=0;a<4;a++){
    #pragma unroll
    for(int rg=0;rg<4;rg++){
      int rw = r0 + wrow*64 + a*16 + quad*4 + rg;
      int bq = rw/8064; int rr = rw - bq*8064;
      int m = rr/1008; int rem = rr - m*1008;
      int p = rem>>4; int d = rem&15;
      int n = (bq*16+d)*8+m;
      ushort* xo = x + (n*NP+p)*256;
      #pragma unroll
      for(int b=0;b<4;b++){
        int c = c0 + wcol*64 + b*16 + l16;
        xo[c] = f2u(acc[b][a][rg]);
      }
    }
  }
}

// ---------------- head ----------------
__global__ void __launch_bounds__(256) k_head(const ushort* __restrict__ x,
    const float* __restrict__ meanv, const float* __restrict__ stdv,
    const float* __restrict__ rs, const float* __restrict__ rb,
    const float* __restrict__ hns, const float* __restrict__ pw,
    const float* __restrict__ qw, float* __restrict__ out)
{
  int n = blockIdx.x, tid = threadIdx.x;
  __shared__ float nb[256];
  __shared__ float red[256];
  float v = u2f(x[(n*NP + 62)*256 + tid]);
  red[tid] = v*v; __syncthreads();
  for(int s=128;s>0;s>>=1){
    if(tid<s) red[tid]+=red[tid+s];
    __syncthreads();
  }
  float rinv = rsqrtf(red[0]*(1.f/256.f)+1e-6f);
  nb[tid] = v*rinv*hns[tid];
  __syncthreads();
  int m = n&7;
  float mu=meanv[n], sd=stdv[n], sc=rs[m], bi=rb[m];
  for(int col=tid; col<384; col+=256){
    float acc=0.f;
    int slot, hh;
    if(col < 96){
      for(int k=0;k<256;k++) acc = fmaf(nb[k], pw[k*96+col], acc);
      slot = 0; hh = col;
    } else {
      int cq = col-96;
      for(int k=0;k<256;k++) acc = fmaf(nb[k], qw[k*288+cq], acc);
      int qi = cq - (cq/3)*3;
      slot = 1 + qi; hh = cq/3;
    }
    float y = (acc - bi)/sc*sd + mu;
    out[(slot*1024 + n)*96 + hh] = y;
  }
}

extern "C" void kernel_launch(void* const* d_in, const int* in_sizes, int n_in,
                              void* d_out, int out_size, void* d_ws, size_t ws_size,
                              hipStream_t stream)
{
  const float* series    = (const float*)d_in[0];
  const float* rs        = (const float*)d_in[1];
  const float* rb        = (const float*)d_in[2];
  const float* up_w      = (const float*)d_in[3];
  const float* lstm_wi   = (const float*)d_in[4];
  const float* lstm_wh   = (const float*)d_in[5];
  const float* lstm_b    = (const float*)d_in[6];
  const float* norm_scale= (const float*)d_in[7];
  const float* wq        = (const float*)d_in[8];
  const float* wk        = (const float*)d_in[9];
  const float* wv        = (const float*)d_in[10];
  const float* wo        = (const float*)d_in[11];
  const float* down_w    = (const float*)d_in[12];
  const float* head_ns   = (const float*)d_in[13];
  const float* point_w   = (const float*)d_in[14];
  const float* quant_w   = (const float*)d_in[15];
  float* out = (float*)d_out;

  float* ws = (float*)d_ws;
  float*  meanv = ws;                       // 1024
  float*  stdv  = meanv + 1024;             // 1024
  float*  rmsi  = stdv  + 1024;             // 64512 (unused; layout stability)
  float*  cst   = rmsi  + 64512;            // 524288 (start reused for flag + detect bytes)
  float*  wodf  = cst   + 524288;           // 524288
  ushort* xbuf  = (ushort*)(wodf + 524288);         // 16515072 bf16
  ushort* hsb   = xbuf  + 16515072;                 // 33030144 bf16
  ushort* qkvb  = hsb   + 33030144;                 // 49545216 bf16
  ushort* wt    = qkvb  + 49545216;                 // 6291456 bf16
  ushort* wqkvt = wt    + 6291456;                  // 1572864 bf16
  ushort* wodt  = wqkvt + 1572864;                  // 524288 bf16
  int*    bar   = (int*)cst;                        // 256B flags + 4x256B detect

  k_revin<<<1024,256,0,stream>>>(series, meanv, stdv, bar);
  k_patch<<<1024,256,0,stream>>>(series, rs, rb, up_w, meanv, stdv, xbuf);
  k_wod<<<dim3(512,4),256,0,stream>>>(wo, down_w, wodf);
  k_tr_wodt<<<dim3(8,16,4),256,0,stream>>>(wodf, wodt);
  k_tr_lstmw<<<dim3(64,24,4),256,0,stream>>>(lstm_wi, lstm_wh, wt);
  k_tr_qkvw<<<dim3(24,16,4),256,0,stream>>>(wq, wk, wv, norm_scale, wqkvt);

  for(int blk=0; blk<4; blk++){
    const ushort* wt_b = wt + blk*2048*768;
    const float*  bb   = lstm_b + blk*2048;
    k_lstm_scan<<<256,256,0,stream>>>(xbuf, hsb, wt_b, bb, (uchar*)bar, blk*NP,
                                      (uchar*)bar + 256 + blk*256);
    k_qkv_m<<<dim3(504,6),256,0,stream>>>(hsb, wqkvt + blk*768*512, qkvb);
    k_attn<<<dim3(4032,8),256,0,stream>>>(qkvb);
    k_bel_m<<<dim3(504,2),256,0,stream>>>(qkvb, wodt + blk*256*512, xbuf);
  }
  k_head<<<1024,256,0,stream>>>(xbuf, meanv, stdv, rs, rb, head_ns, point_w, quant_w, out);
}

// Round 10
// 3190.774 us; speedup vs baseline: 1.8549x; 1.1298x over previous
//
#include <hip/hip_runtime.h>
#include <hip/hip_bf16.h>

#define NP 63   // number of patches

typedef __attribute__((ext_vector_type(8))) short short8;
typedef __attribute__((ext_vector_type(4))) float f32x4;
typedef __attribute__((ext_vector_type(4))) int i32x4;
typedef unsigned char uchar;

__device__ __forceinline__ float sigf(float x){ return 1.0f/(1.0f+expf(-x)); }
__device__ __forceinline__ float u2f(ushort u){ __hip_bfloat16 h; *(ushort*)&h = u; return __bfloat162float(h); }
__device__ __forceinline__ ushort f2u(float f){ __hip_bfloat16 h = __float2bfloat16(f); return *(ushort*)&h; }

// HW transcendental gate functions (scan epilogue critical path):
// v_exp_f32 = 2^x (1 ulp), v_rcp_f32 (~22-bit). Args clamped to +-126 for inf-safety.
__device__ __forceinline__ float fexp2(float x){ float r; asm("v_exp_f32 %0, %1" : "=v"(r) : "v"(x)); return r; }
__device__ __forceinline__ float frcp (float x){ float r; asm("v_rcp_f32 %0, %1" : "=v"(r) : "v"(x)); return r; }
#define LOG2E 1.442695040888963f
__device__ __forceinline__ float sig_fast(float x){
  float a = fminf(fmaxf(-LOG2E*x, -126.f), 126.f);
  return frcp(1.f + fexp2(a));
}
__device__ __forceinline__ float tanh_fast(float x){
  float a = fminf(fmaxf(-2.f*LOG2E*x, -126.f), 126.f);
  float e = fexp2(a);
  return (1.f - e) * frcp(1.f + e);
}

// ---------------- RevIN stats (+ zero persistent-scan flag bytes) ----------------
__global__ void __launch_bounds__(256) k_revin(const float* __restrict__ series,
    float* __restrict__ meanv, float* __restrict__ stdv, int* __restrict__ bar)
{
  int n = blockIdx.x, tid = threadIdx.x;
  if(n==0 && tid<64) bar[tid] = 0;   // 256 flag bytes (16 groups x 16 blocks)
  __shared__ float s1[256], s2[256];
  const float* p = series + n*512;
  float a = 0.f, b = 0.f;
  for(int t=tid;t<512;t+=256){ float v=p[t]; a+=v; b+=v*v; }
  s1[tid]=a; s2[tid]=b; __syncthreads();
  for(int s=128;s>0;s>>=1){
    if(tid<s){ s1[tid]+=s1[tid+s]; s2[tid]+=s2[tid+s]; }
    __syncthreads();
  }
  if(tid==0){
    float mu = s1[0]*(1.f/512.f);
    float var = fmaxf(s2[0]*(1.f/512.f) - mu*mu, 0.f);
    meanv[n]=mu; stdv[n]=sqrtf(var+1e-5f);
  }
}

// ---------------- patch embed -> bf16 xbuf ----------------
__global__ void __launch_bounds__(256) k_patch(const float* __restrict__ series,
    const float* __restrict__ rs, const float* __restrict__ rb,
    const float* __restrict__ up_w, const float* __restrict__ meanv,
    const float* __restrict__ stdv, ushort* __restrict__ x)
{
  int n = blockIdx.x, tid = threadIdx.x;
  int m = n & 7;
  __shared__ float sn[512];
  float mu = meanv[n], sd = stdv[n];
  float A = rs[m]/sd, C = rb[m] - mu*A;
  const float* p = series + n*512;
  for(int t=tid;t<512;t+=256) sn[t] = p[t]*A + C;
  __syncthreads();
  float w[16];
  #pragma unroll
  for(int i=0;i<16;i++) w[i] = up_w[i*256+tid];
  ushort* xo = x + n*(NP*256);
  for(int pi=0;pi<NP;pi++){
    float acc=0.f;
    #pragma unroll
    for(int i=0;i<16;i++) acc = fmaf(sn[pi*8+i], w[i], acc);
    xo[pi*256+tid] = f2u(acc);
  }
}

// ---------------- W_od = wo @ down_w (f32) ----------------
__global__ void __launch_bounds__(256) k_wod(const float* __restrict__ wo,
    const float* __restrict__ dw, float* __restrict__ wod)
{
  int i = blockIdx.x, blk = blockIdx.y, tid = threadIdx.x;
  __shared__ float row[512];
  const float* wr = wo + (blk*512 + i)*512;
  for(int k=tid;k<512;k+=256) row[k]=wr[k];
  __syncthreads();
  const float* d = dw + blk*512*256;
  float acc=0.f;
  for(int k=0;k<512;k++) acc = fmaf(row[k], d[k*256+tid], acc);
  wod[(blk*512+i)*256+tid]=acc;
}

// ---------------- transpose wod (512k x 256n) -> wodt bf16 [256][512] ----------------
__global__ void __launch_bounds__(256) k_tr_wodt(const float* __restrict__ wod, ushort* __restrict__ wodt)
{
  __shared__ float tile[32][33];
  int blk = blockIdx.z;
  int n0 = blockIdx.x*32, k0 = blockIdx.y*32;
  int tid = threadIdx.x;
  #pragma unroll
  for(int i=0;i<4;i++){
    int idx = tid + 256*i; int kl = idx>>5, nl = idx&31;
    tile[kl][nl] = wod[blk*512*256 + (k0+kl)*256 + n0+nl];
  }
  __syncthreads();
  #pragma unroll
  for(int i=0;i<4;i++){
    int idx = tid + 256*i; int nl = idx>>5, kl = idx&31;
    wodt[blk*256*512 + (n0+nl)*512 + k0+kl] = f2u(tile[kl][nl]);
  }
}

// ---------------- transpose [wi;wh] (768k x 2048n) -> wt bf16 [2048][768] ----------------
__global__ void __launch_bounds__(256) k_tr_lstmw(const float* __restrict__ wi,
    const float* __restrict__ wh, ushort* __restrict__ wt)
{
  __shared__ float tile[32][33];
  int blk = blockIdx.z;
  int n0 = blockIdx.x*32, k0 = blockIdx.y*32;
  int tid = threadIdx.x;
  #pragma unroll
  for(int i=0;i<4;i++){
    int idx = tid + 256*i; int kl = idx>>5, nl = idx&31;
    int k = k0+kl, n = n0+nl;
    float v = (k<256) ? wi[blk*256*2048 + k*2048 + n]
                      : wh[blk*512*2048 + (k-256)*2048 + n];
    tile[kl][nl] = v;
  }
  __syncthreads();
  #pragma unroll
  for(int i=0;i<4;i++){
    int idx = tid + 256*i; int nl = idx>>5, kl = idx&31;
    wt[blk*2048*768 + (n0+nl)*768 + k0+kl] = f2u(tile[kl][nl]);
  }
}

// ---------------- transpose [wq|wk|wv] (512k x 768n), fold ns[k] -> wqkvt bf16 [768][512] ----------------
__global__ void __launch_bounds__(256) k_tr_qkvw(const float* __restrict__ wq,
    const float* __restrict__ wk, const float* __restrict__ wv,
    const float* __restrict__ ns, ushort* __restrict__ wqkvt)
{
  __shared__ float tile[32][33];
  int blk = blockIdx.z;
  int n0 = blockIdx.x*32, k0 = blockIdx.y*32;
  int tid = threadIdx.x;
  #pragma unroll
  for(int i=0;i<4;i++){
    int idx = tid + 256*i; int kl = idx>>5, nl = idx&31;
    int k = k0+kl, n = n0+nl;
    float v;
    if(n < 512)      v = wq[blk*512*512 + k*512 + n];
    else if(n < 640) v = wk[blk*512*128 + k*128 + (n-512)];
    else             v = wv[blk*512*128 + k*128 + (n-640)];
    tile[kl][nl] = v * ns[blk*512 + k];
  }
  __syncthreads();
  #pragma unroll
  for(int i=0;i<4;i++){
    int idx = tid + 256*i; int nl = idx>>5, kl = idx&31;
    wqkvt[blk*768*512 + (n0+nl)*512 + k0+kl] = f2u(tile[kl][nl]);
  }
}

// ---------------- persistent LSTM scan: all 63 steps in one launch (r3-verified structure) ----------------
// 256 blocks x 256 thr, 1 block/CU (132 KB LDS). Block = (row group g: 64 rows) x (jj tile y: 32 jj x 4 gates).
// Cross-block dep row-local: 16-block group barrier per step via BYTE FLAGS in one 16B line.
// h stores coalesced: epilogue -> LDS staging tile -> one 16B sc1 store/thread.
// wi B-frags in regs; wh (k 256..767) fully LDS-resident, XOR-swizzled. c-state in regs.
// Epilogue gates use HW v_exp/v_rcp (critical-path VALU cut ~4x vs libm).
__global__ void __launch_bounds__(256,1) k_lstm_scan(
    const ushort* __restrict__ x, ushort* __restrict__ hs,
    const ushort* __restrict__ wt, const float* __restrict__ bias,
    uchar* __restrict__ flags, int tagbase)
{
  __shared__ __align__(16) short Bwh[128*512];     // 128 KB: c row (gate*32+jjl) x k 256..767, swizzled
  __shared__ __align__(16) ushort hstage[64*32];   // 4 KB h staging
  int fb = blockIdx.x;
  // XCD-grouping heuristic: members of a barrier group share blockIdx%8 -> same XCD
  int g = (fb & 7) | ((fb >> 4) & 8);
  int y = (fb >> 3) & 15;
  int n0 = g*64, jj0 = y*32;
  int tid = threadIdx.x;
  int wv = tid>>6, lane = tid&63, quad = lane>>4, l16 = lane&15;
  int wrow = wv>>1, wcol = wv&1;

  // fill Bwh: 128 c-rows x 64 short8 (k 256..767), 16B-block XOR swizzle by (c&7)
  for(int i=tid; i<8192; i+=256){
    int c = i>>6, kb = i&63;
    short8 v = *(const short8*)(wt + ((c>>5)*512 + jj0 + (c&31))*768 + 256 + kb*8);
    *(short8*)((char*)Bwh + c*1024 + ((kb*16) ^ ((c&7)<<4))) = v;
  }
  // wi B-fragments -> regs (4 gates x 8 k-chunks)
  int jj = jj0 + wcol*16 + l16;
  short8 bwi[4][8];
  #pragma unroll
  for(int gg=0; gg<4; gg++){
    const ushort* wp = wt + (gg*512 + jj)*768 + quad*8;
    #pragma unroll
    for(int ck=0; ck<8; ck++) bwi[gg][ck] = *(const short8*)(wp + ck*32);
  }
  float bI=bias[jj], bF=bias[512+jj], bG=bias[1024+jj], bO=bias[1536+jj];
  float cs[2][4];
  #pragma unroll
  for(int a=0;a<2;a++){
    #pragma unroll
    for(int r=0;r<4;r++) cs[a][r]=0.f;
  }
  const ushort* xb0 = x  + (n0 + wrow*32 + l16)*(NP*256) + quad*8;
  const ushort* hb0 = hs + (n0 + wrow*32 + l16)*(NP*512) + quad*8;
  int xorb = (l16&7)<<4;
  uchar* myflag = flags + g*16 + y;
  const uchar* gflags = flags + g*16;
  __syncthreads();

  for(int t=0; t<NP; ++t){
    f32x4 acc[4][2];
    #pragma unroll
    for(int gg=0; gg<4; gg++){ acc[gg][0]=(f32x4){0.f,0.f,0.f,0.f}; acc[gg][1]=(f32x4){0.f,0.f,0.f,0.f}; }

    // ---- x_t @ wi (k 0..255) — no recurrent dep, runs before the group wait ----
    #pragma unroll
    for(int ck=0; ck<8; ck++){
      short8 a0 = *(const short8*)(xb0 + t*256 + ck*32);
      short8 a1 = *(const short8*)(xb0 + 16*(NP*256) + t*256 + ck*32);
      #pragma unroll
      for(int gg=0; gg<4; gg++){
        acc[gg][0] = __builtin_amdgcn_mfma_f32_16x16x32_bf16(a0, bwi[gg][ck], acc[gg][0], 0,0,0);
        acc[gg][1] = __builtin_amdgcn_mfma_f32_16x16x32_bf16(a1, bwi[gg][ck], acc[gg][1], 0,0,0);
      }
    }

    if(t > 0){
      // ---- group barrier: all 16 flag bytes >= tagbase+t (monotonic; '>=' tolerates fast blocks) ----
      if(tid==0){
        uint tag = (uint)(tagbase + t);
        while(1){
          i32x4 f;
          asm volatile("global_load_dwordx4 %0, %1, off sc0 sc1\n\ts_waitcnt vmcnt(0)"
                       : "=&v"(f) : "v"(gflags) : "memory");
          uint ok = 1u;
          #pragma unroll
          for(int q=0;q<4;q++){
            uint w = (uint)f[q];
            if(( w      &0xffu) < tag) ok=0;
            if(((w>>8 ) &0xffu) < tag) ok=0;
            if(((w>>16) &0xffu) < tag) ok=0;
            if( (w>>24)         < tag) ok=0;
          }
          if(ok) break;
          __builtin_amdgcn_s_sleep(1);
        }
      }
      __syncthreads();

      const ushort* hb = hb0 + (t-1)*512;
      // ---- h @ wh, k 256..767 entirely from LDS ----
      #pragma unroll
      for(int ck=0; ck<16; ck++){
        short8 a0 = *(const short8*)(hb + ck*32);
        short8 a1 = *(const short8*)(hb + 16*(NP*512) + ck*32);
        #pragma unroll
        for(int gg=0; gg<4; gg++){
          int c = gg*32 + wcol*16 + l16;
          short8 bh = *(short8*)((char*)Bwh + c*1024 + ((ck*64 + quad*16) ^ xorb));
          acc[gg][0] = __builtin_amdgcn_mfma_f32_16x16x32_bf16(a0, bh, acc[gg][0], 0,0,0);
          acc[gg][1] = __builtin_amdgcn_mfma_f32_16x16x32_bf16(a1, bh, acc[gg][1], 0,0,0);
        }
      }
    }

    // ---- gates (HW exp/rcp) + c-state (regs) + h -> LDS staging (swizzled) ----
    #pragma unroll
    for(int a=0;a<2;a++){
      #pragma unroll
      for(int r=0;r<4;r++){
        int rowl = wrow*32 + a*16 + quad*4 + r;
        float zi=acc[0][a][r]+bI, zf=acc[1][a][r]+bF, zg=acc[2][a][r]+bG, zo=acc[3][a][r]+bO;
        float c = sig_fast(zf)*cs[a][r] + sig_fast(zi)*tanh_fast(zg);
        cs[a][r] = c;
        float hv = sig_fast(zo)*tanh_fast(c);
        int coll = wcol*16 + l16;
        int off = rowl*64 + ((coll*2) ^ (((rowl>>2)&3)<<4));
        *(ushort*)((char*)hstage + off) = f2u(hv);
      }
    }
    __syncthreads();
    // ---- coalesced device-visible h store: 256 threads x 16B ----
    {
      int rowl = tid>>2, c0b = (tid&3)*16;
      int off = rowl*64 + (c0b ^ (((rowl>>2)&3)<<4));
      i32x4 vv = *(const i32x4*)((const char*)hstage + off);
      ushort* gp = hs + ((size_t)(n0+rowl)*NP + t)*512 + jj0 + (tid&3)*8;
      asm volatile("global_store_dwordx4 %0, %1, off sc0 sc1" :: "v"(gp), "v"(vv) : "memory");
    }
    __syncthreads();   // drains vmcnt(0) per wave -> all h stores at coherence point
    if(tid==0 && t < NP-1){
      uint v = (uint)(tagbase + t + 1);
      asm volatile("global_store_byte %0, %1, off sc0 sc1" :: "v"(myflag), "v"(v) : "memory");
    }
  }
}

// ---------------- qkv GEMM via MFMA: 64512 x 768, K=512; 128x128 tile; rms fused ----------------
__global__ void __launch_bounds__(256) k_qkv_m(
    const ushort* __restrict__ hs, const ushort* __restrict__ wqkvt,
    ushort* __restrict__ qkv)
{
  __shared__ short As[128*40];
  __shared__ short Bs[128*40];
  __shared__ float rvs[128];
  int tid = threadIdx.x;
  int r0 = blockIdx.x*128, c0 = blockIdx.y*128;
  int wv = tid>>6, lane = tid&63, quad = lane>>4, l16 = lane&15;
  int wrow = wv>>1, wcol = wv&1;
  int arow0 = tid>>2, akp = tid&3;
  const ushort* aptr[2];
  #pragma unroll
  for(int i=0;i<2;i++){
    int r = r0 + arow0 + i*64;
    int bq = r/8064; int rr = r - bq*8064;
    int m = rr/1008; int rem = rr - m*1008;
    int p = rem>>4; int d = rem&15;
    int n = (bq*16+d)*8+m;
    aptr[i] = hs + (n*NP+p)*512 + akp*8;
  }
  f32x4 acc[4][4];
  #pragma unroll
  for(int b=0;b<4;b++){
    #pragma unroll
    for(int a=0;a<4;a++) acc[b][a] = (f32x4){0.f,0.f,0.f,0.f};
  }
  float ssq0 = 0.f, ssq1 = 0.f;
  for(int k0=0;k0<512;k0+=32){
    {
      short8 av = *(const short8*)(aptr[0] + k0);
      *(short8*)&As[arow0*40 + akp*8] = av;
      #pragma unroll
      for(int e=0;e<8;e++){ float vv = u2f((ushort)av[e]); ssq0 = fmaf(vv, vv, ssq0); }
    }
    {
      short8 av = *(const short8*)(aptr[1] + k0);
      *(short8*)&As[(arow0+64)*40 + akp*8] = av;
      #pragma unroll
      for(int e=0;e<8;e++){ float vv = u2f((ushort)av[e]); ssq1 = fmaf(vv, vv, ssq1); }
    }
    #pragma unroll
    for(int i=0;i<2;i++){
      int pc = tid + 256*i; int rl=pc>>2, kp=pc&3;
      *(short8*)&Bs[rl*40+kp*8] = *(const short8*)(wqkvt + (c0+rl)*512 + k0 + kp*8);
    }
    __syncthreads();
    short8 af[4], bfr[4];
    #pragma unroll
    for(int a=0;a<4;a++) af[a] = *(short8*)&As[(wrow*64 + a*16 + l16)*40 + quad*8];
    #pragma unroll
    for(int b=0;b<4;b++) bfr[b] = *(short8*)&Bs[(wcol*64 + b*16 + l16)*40 + quad*8];
    #pragma unroll
    for(int b=0;b<4;b++){
      #pragma unroll
      for(int a=0;a<4;a++)
        acc[b][a] = __builtin_amdgcn_mfma_f32_16x16x32_bf16(af[a], bfr[b], acc[b][a], 0,0,0);
    }
    __syncthreads();
  }
  ssq0 += __shfl_xor(ssq0, 1); ssq0 += __shfl_xor(ssq0, 2);
  ssq1 += __shfl_xor(ssq1, 1); ssq1 += __shfl_xor(ssq1, 2);
  if(akp==0){
    rvs[arow0]    = rsqrtf(ssq0*(1.f/512.f)+1e-6f);
    rvs[arow0+64] = rsqrtf(ssq1*(1.f/512.f)+1e-6f);
  }
  __syncthreads();
  #pragma unroll
  for(int a=0;a<4;a++){
    #pragma unroll
    for(int rg=0;rg<4;rg++){
      int rowl = wrow*64 + a*16 + quad*4 + rg;
      int rw = r0 + rowl;
      float rv = rvs[rowl];
      #pragma unroll
      for(int b=0;b<4;b++){
        int c = c0 + wcol*64 + b*16 + l16;
        qkv[rw*768 + c] = f2u(acc[b][a][rg] * rv);
      }
    }
  }
}

// ---------------- attention (bf16 qkv buffer): per (row16-group, head) ----------------
__global__ void __launch_bounds__(256) k_attn(ushort* __restrict__ qkv)
{
  int r3 = blockIdx.x, h = blockIdx.y;
  int tid = threadIdx.x;
  __shared__ float qs[16][64];
  __shared__ float ks[16][65];
  __shared__ float vs[16][64];
  __shared__ float P[16][17];
  ushort* base = qkv + r3*16*768;
  int xx = tid&63, s4 = tid>>6;
  int kvh = (h>>2)*64;
  #pragma unroll
  for(int a=0;a<4;a++){
    int s = s4 + 4*a;
    qs[s][xx] = u2f(base[s*768 + h*64 + xx]);
    ks[s][xx] = u2f(base[s*768 + 512 + kvh + xx]);
    vs[s][xx] = u2f(base[s*768 + 640 + kvh + xx]);
  }
  __syncthreads();
  int i = tid>>4, j = tid&15;
  float sc = 0.f;
  #pragma unroll
  for(int xq=0;xq<64;xq++) sc = fmaf(qs[i][xq], ks[j][xq], sc);
  P[i][j] = sc*0.125f;
  __syncthreads();
  float row[16];
  #pragma unroll
  for(int jj=0;jj<16;jj++) row[jj] = P[i][jj];
  float mx = row[0];
  #pragma unroll
  for(int jj=1;jj<16;jj++) mx = fmaxf(mx, row[jj]);
  float sum = 0.f;
  #pragma unroll
  for(int jj=0;jj<16;jj++) sum += expf(row[jj]-mx);
  float pme = expf(row[j]-mx)/sum;
  __syncthreads();
  P[i][j] = pme;
  __syncthreads();
  #pragma unroll
  for(int a=0;a<4;a++){
    int s = s4 + 4*a;
    float o = 0.f;
    #pragma unroll
    for(int jj=0;jj<16;jj++) o = fmaf(P[s][jj], vs[jj][xx], o);
    base[s*768 + h*64 + xx] = f2u(o);
  }
}

// ---------------- bel GEMM via MFMA: O(64512x512 in qkv) @ wodt^T -> scatter bf16 xbuf ----------------
__global__ void __launch_bounds__(256) k_bel_m(
    const ushort* __restrict__ qkv, const ushort* __restrict__ wodt,
    ushort* __restrict__ x)
{
  __shared__ short As[128*40];
  __shared__ short Bs[128*40];
  int tid = threadIdx.x;
  int r0 = blockIdx.x*128, c0 = blockIdx.y*128;
  int wv = tid>>6, lane = tid&63, quad = lane>>4, l16 = lane&15;
  int wrow = wv>>1, wcol = wv&1;
  int arow0 = tid>>2, akp = tid&3;
  const ushort* aptr0 = qkv + (r0+arow0)*768 + akp*8;
  const ushort* aptr1 = qkv + (r0+arow0+64)*768 + akp*8;
  f32x4 acc[4][4];
  #pragma unroll
  for(int b=0;b<4;b++){
    #pragma unroll
    for(int a=0;a<4;a++) acc[b][a] = (f32x4){0.f,0.f,0.f,0.f};
  }
  for(int k0=0;k0<512;k0+=32){
    *(short8*)&As[arow0*40 + akp*8]      = *(const short8*)(aptr0 + k0);
    *(short8*)&As[(arow0+64)*40 + akp*8] = *(const short8*)(aptr1 + k0);
    #pragma unroll
    for(int i=0;i<2;i++){
      int pc = tid + 256*i; int rl=pc>>2, kp=pc&3;
      *(short8*)&Bs[rl*40+kp*8] = *(const short8*)(wodt + (c0+rl)*512 + k0 + kp*8);
    }
    __syncthreads();
    short8 af[4], bfr[4];
    #pragma unroll
    for(int a=0;a<4;a++) af[a] = *(short8*)&As[(wrow*64 + a*16 + l16)*40 + quad*8];
    #pragma unroll
    for(int b=0;b<4;b++) bfr[b] = *(short8*)&Bs[(wcol*64 + b*16 + l16)*40 + quad*8];
    #pragma unroll
    for(int b=0;b<4;b++){
      #pragma unroll
      for(int a=0;a<4;a++)
        acc[b][a] = __builtin_amdgcn_mfma_f32_16x16x32_bf16(af[a], bfr[b], acc[b][a], 0,0,0);
    }
    __syncthreads();
  }
  #pragma unroll
  for(int a=0;a<4;a++){
    #pragma unroll
    for(int rg=0;rg<4;rg++){
      int rw = r0 + wrow*64 + a*16 + quad*4 + rg;
      int bq = rw/8064; int rr = rw - bq*8064;
      int m = rr/1008; int rem = rr - m*1008;
      int p = rem>>4; int d = rem&15;
      int n = (bq*16+d)*8+m;
      ushort* xo = x + (n*NP+p)*256;
      #pragma unroll
      for(int b=0;b<4;b++){
        int c = c0 + wcol*64 + b*16 + l16;
        xo[c] = f2u(acc[b][a][rg]);
      }
    }
  }
}

// ---------------- head ----------------
__global__ void __launch_bounds__(256) k_head(const ushort* __restrict__ x,
    const float* __restrict__ meanv, const float* __restrict__ stdv,
    const float* __restrict__ rs, const float* __restrict__ rb,
    const float* __restrict__ hns, const float* __restrict__ pw,
    const float* __restrict__ qw, float* __restrict__ out)
{
  int n = blockIdx.x, tid = threadIdx.x;
  __shared__ float nb[256];
  __shared__ float red[256];
  float v = u2f(x[(n*NP + 62)*256 + tid]);
  red[tid] = v*v; __syncthreads();
  for(int s=128;s>0;s>>=1){
    if(tid<s) red[tid]+=red[tid+s];
    __syncthreads();
  }
  float rinv = rsqrtf(red[0]*(1.f/256.f)+1e-6f);
  nb[tid] = v*rinv*hns[tid];
  __syncthreads();
  int m = n&7;
  float mu=meanv[n], sd=stdv[n], sc=rs[m], bi=rb[m];
  for(int col=tid; col<384; col+=256){
    float acc=0.f;
    int slot, hh;
    if(col < 96){
      for(int k=0;k<256;k++) acc = fmaf(nb[k], pw[k*96+col], acc);
      slot = 0; hh = col;
    } else {
      int cq = col-96;
      for(int k=0;k<256;k++) acc = fmaf(nb[k], qw[k*288+cq], acc);
      int qi = cq - (cq/3)*3;
      slot = 1 + qi; hh = cq/3;
    }
    float y = (acc - bi)/sc*sd + mu;
    out[(slot*1024 + n)*96 + hh] = y;
  }
}

extern "C" void kernel_launch(void* const* d_in, const int* in_sizes, int n_in,
                              void* d_out, int out_size, void* d_ws, size_t ws_size,
                              hipStream_t stream)
{
  const float* series    = (const float*)d_in[0];
  const float* rs        = (const float*)d_in[1];
  const float* rb        = (const float*)d_in[2];
  const float* up_w      = (const float*)d_in[3];
  const float* lstm_wi   = (const float*)d_in[4];
  const float* lstm_wh   = (const float*)d_in[5];
  const float* lstm_b    = (const float*)d_in[6];
  const float* norm_scale= (const float*)d_in[7];
  const float* wq        = (const float*)d_in[8];
  const float* wk        = (const float*)d_in[9];
  const float* wv        = (const float*)d_in[10];
  const float* wo        = (const float*)d_in[11];
  const float* down_w    = (const float*)d_in[12];
  const float* head_ns   = (const float*)d_in[13];
  const float* point_w   = (const float*)d_in[14];
  const float* quant_w   = (const float*)d_in[15];
  float* out = (float*)d_out;

  float* ws = (float*)d_ws;
  float*  meanv = ws;                       // 1024
  float*  stdv  = meanv + 1024;             // 1024
  float*  rmsi  = stdv  + 1024;             // 64512 (unused; layout stability)
  float*  cst   = rmsi  + 64512;            // 524288 (start reused for flag bytes)
  float*  wodf  = cst   + 524288;           // 524288
  ushort* xbuf  = (ushort*)(wodf + 524288);         // 16515072 bf16
  ushort* hsb   = xbuf  + 16515072;                 // 33030144 bf16
  ushort* qkvb  = hsb   + 33030144;                 // 49545216 bf16
  ushort* wt    = qkvb  + 49545216;                 // 6291456 bf16
  ushort* wqkvt = wt    + 6291456;                  // 1572864 bf16
  ushort* wodt  = wqkvt + 1572864;                  // 524288 bf16
  int*    bar   = (int*)cst;                        // 256 flag bytes (16 groups x 16 blocks)

  k_revin<<<1024,256,0,stream>>>(series, meanv, stdv, bar);
  k_patch<<<1024,256,0,stream>>>(series, rs, rb, up_w, meanv, stdv, xbuf);
  k_wod<<<dim3(512,4),256,0,stream>>>(wo, down_w, wodf);
  k_tr_wodt<<<dim3(8,16,4),256,0,stream>>>(wodf, wodt);
  k_tr_lstmw<<<dim3(64,24,4),256,0,stream>>>(lstm_wi, lstm_wh, wt);
  k_tr_qkvw<<<dim3(24,16,4),256,0,stream>>>(wq, wk, wv, norm_scale, wqkvt);

  for(int blk=0; blk<4; blk++){
    const ushort* wt_b = wt + blk*2048*768;
    const float*  bb   = lstm_b + blk*2048;
    k_lstm_scan<<<256,256,0,stream>>>(xbuf, hsb, wt_b, bb, (uchar*)bar, blk*NP);
    k_qkv_m<<<dim3(504,6),256,0,stream>>>(hsb, wqkvt + blk*768*512, qkvb);
    k_attn<<<dim3(4032,8),256,0,stream>>>(qkvb);
    k_bel_m<<<dim3(504,2),256,0,stream>>>(qkvb, wodt + blk*256*512, xbuf);
  }
  k_head<<<1024,256,0,stream>>>(xbuf, meanv, stdv, rs, rb, head_ns, point_w, quant_w, out);
}